// Round 1
// baseline (1033.591 us; speedup 1.0000x reference)
//
#include <hip/hip_runtime.h>
#include <math.h>

#define NB 8
#define NC 96
#define HF 64
#define HS 32
#define L 1024
#define MN 1536   // 96 * 16 taps

// workspace layout (float offsets)
//  G    : [NB][L][L]      gram matrices, later overwritten by F1T
//  A    : [NB][L][L]      normalized raw scores, later overwritten by Yt (softmax probs, [p][k])
//  RW   : [NB][L][MN]     gathered deconv weight patches, K-axis in cm l-order
//  INVN : [NB][L]         1/max(norm_l, eps)
#define G_OFF   0ull
#define A_OFF   (8ull * 1024 * 1024)
#define RW_OFF  (16ull * 1024 * 1024)
#define N_OFF   (RW_OFF + 8ull * 1024 * 1536)
// total floats: 29,368,320  -> ~117.5 MB of d_ws

// ---------------------------------------------------------------------------
// K0: inv patch norms.  norm_l^2 = sum over 3x3 neighborhood (zero-padded) of
// sq[q] = sum_c bs[c,q]^2.  One block per batch, 1024 threads (one per pos).
__global__ void k0_norm(const float* __restrict__ b, float* __restrict__ ws) {
    int n = blockIdx.x;
    int t = threadIdx.x;            // position q = (i,j), row-major
    int i = t >> 5, j = t & 31;
    __shared__ float sq[1024];
    const float* bp = b + (size_t)n * NC * HF * HF;
    float s = 0.f;
    for (int c = 0; c < NC; ++c) {
        float v = bp[((size_t)c * HF + 2 * i) * HF + 2 * j];
        s += v * v;
    }
    sq[t] = s;
    __syncthreads();
    float nsq = 0.f;
    #pragma unroll
    for (int dy = -1; dy <= 1; ++dy)
        #pragma unroll
        for (int dx = -1; dx <= 1; ++dx) {
            int ii = i + dy, jj = j + dx;
            if (ii >= 0 && ii < HS && jj >= 0 && jj < HS) nsq += sq[ii * HS + jj];
        }
    ws[N_OFF + (size_t)n * L + t] = 1.f / fmaxf(sqrtf(nsq), 1e-4f);
}

// ---------------------------------------------------------------------------
// K1: Gram matrix G[l][p] = sum_c bs[c,l] * fs[c,p].  64x64 tile per block,
// 4x4 micro-tile per thread, K staged in 32-channel chunks.
__global__ __launch_bounds__(256) void k1_gram(const float* __restrict__ f,
                                               const float* __restrict__ b,
                                               float* __restrict__ ws) {
    int n = blockIdx.z;
    int l0 = blockIdx.y * 64, p0 = blockIdx.x * 64;
    int t = threadIdx.x;
    int tp = t >> 4, tm = t & 15;
    __shared__ float Bt[32][68];
    __shared__ float Ft[32][68];
    float acc[4][4] = {};
    const float* bp = b + (size_t)n * NC * HF * HF;
    const float* fp = f + (size_t)n * NC * HF * HF;
    int ly0 = l0 >> 5;   // blockIdx.y*2
    int py0 = p0 >> 5;
    for (int c0 = 0; c0 < NC; c0 += 32) {
        #pragma unroll
        for (int e = 0; e < 8; ++e) {
            int idx = t + e * 256;     // 0..2047
            int q = idx & 63, cl = idx >> 6;
            int c = c0 + cl;
            Bt[cl][q] = bp[((size_t)c * HF + 2 * (ly0 + (q >> 5))) * HF + 2 * (q & 31)];
            Ft[cl][q] = fp[((size_t)c * HF + 2 * (py0 + (q >> 5))) * HF + 2 * (q & 31)];
        }
        __syncthreads();
        for (int cl = 0; cl < 32; ++cl) {
            float4 a4 = *(const float4*)&Bt[cl][tp * 4];
            float4 b4 = *(const float4*)&Ft[cl][tm * 4];
            float av[4] = {a4.x, a4.y, a4.z, a4.w};
            float bv[4] = {b4.x, b4.y, b4.z, b4.w};
            #pragma unroll
            for (int aa = 0; aa < 4; ++aa)
                #pragma unroll
                for (int bb = 0; bb < 4; ++bb)
                    acc[aa][bb] += av[aa] * bv[bb];
        }
        __syncthreads();
    }
    float* G = ws + G_OFF + (size_t)n * L * L;
    #pragma unroll
    for (int aa = 0; aa < 4; ++aa) {
        int l = l0 + tp * 4 + aa;
        float4 v = make_float4(acc[aa][0], acc[aa][1], acc[aa][2], acc[aa][3]);
        *(float4*)&G[(size_t)l * L + p0 + tm * 4] = v;
    }
}

// ---------------------------------------------------------------------------
// K2: raw scores A[l][p] = invn[l] * sum over 9 shifts (dy,dx) of
// G[(ly+dy, lx+dx)][(py+dy, px+dx)] with boundary masks (zero-padding of both
// the bs-patches and the fs conv).
__global__ void k2_score(float* __restrict__ ws) {
    int n = blockIdx.y, l = blockIdx.x, t = threadIdx.x;
    int ly = l >> 5, lx = l & 31;
    const float* G = ws + G_OFF + (size_t)n * L * L;
    float invn = ws[N_OFF + (size_t)n * L + l];
    float* A = ws + A_OFF + (size_t)n * L * L + (size_t)l * L;
    for (int e = 0; e < 4; ++e) {
        int p = t + e * 256;
        int py = p >> 5, px = p & 31;
        float s = 0.f;
        #pragma unroll
        for (int dy = -1; dy <= 1; ++dy) {
            int lyy = ly + dy;
            int pyy = py + dy;
            if (lyy < 0 || lyy >= HS) continue;
            #pragma unroll
            for (int dx = -1; dx <= 1; ++dx) {
                int lxx = lx + dx;
                int pxx = px + dx;
                if (lxx >= 0 && lxx < HS && pyy >= 0 && pyy < HS && pxx >= 0 && pxx < HS)
                    s += G[(size_t)(lyy * HS + lxx) * L + pyy * HS + pxx];
            }
        }
        A[p] = invn * s;
    }
}

// ---------------------------------------------------------------------------
// K3: first fuse (3-tap diagonal over flat row-major indices) + transpose:
// F1T[j][i] = sum_{d=-1..1} A[i+d][j+d]  (OOB -> 0).  32x32 tile via LDS.
__global__ void k3_fuse1t(float* __restrict__ ws) {
    int n = blockIdx.z;
    int i0 = blockIdx.y * 32, j0 = blockIdx.x * 32;
    int t = threadIdx.x;
    __shared__ float sA[34][35];
    const float* A = ws + A_OFF + (size_t)n * L * L;
    for (int e = 0; e < 5; ++e) {
        int idx = t + e * 256;
        if (idx < 34 * 34) {
            int a = idx / 34, bq = idx % 34;
            int gi = i0 - 1 + a, gj = j0 - 1 + bq;
            float v = 0.f;
            if (gi >= 0 && gi < L && gj >= 0 && gj < L) v = A[(size_t)gi * L + gj];
            sA[a][bq] = v;
        }
    }
    __syncthreads();
    float* F1T = ws + G_OFF + (size_t)n * L * L;   // overwrite G
    #pragma unroll
    for (int e = 0; e < 4; ++e) {
        int idx = t + e * 256;
        int jl = idx >> 5, il = idx & 31;
        float v = sA[il][jl] + sA[il + 1][jl + 1] + sA[il + 2][jl + 2];
        F1T[(size_t)(j0 + jl) * L + i0 + il] = v;
    }
}

// ---------------------------------------------------------------------------
// K4: second fuse (diagonal 3-tap over column-major flattening) + scale +
// softmax over l for fixed p.  One block per (n, p).  The cm2rm index
// scramble is absorbed by a padded 32x33 LDS layout (conflict-free both ways).
// Output: Yt[p][k] = softmax prob, k = column-major l index (lx*32+ly).
__global__ void k4_fuse2_softmax(float* __restrict__ ws) {
    int n = blockIdx.y, p = blockIdx.x, t = threadIdx.x;
    int py = p >> 5, px = p & 31;
    int Jc = px * HS + py;            // cm-flat index of p
    __shared__ float s3[3][32][33];
    __shared__ float red[256];
    const float* F1T = ws + G_OFF + (size_t)n * L * L;
    bool rowok[3];
    #pragma unroll
    for (int d = 0; d < 3; ++d) {
        int Jd = Jc + d - 1;
        rowok[d] = (Jd >= 0 && Jd < L);
        int rd = rowok[d] ? ((Jd & 31) * HS + (Jd >> 5)) : 0;   // cm2rm(Jd)
        const float* row = F1T + (size_t)rd * L;
        for (int e = 0; e < 4; ++e) {
            int i_ = t + e * 256;
            float v = rowok[d] ? row[i_] : 0.f;
            s3[d][i_ & 31][i_ >> 5] = v;    // element F1T[rd][i] at [i%32][i/32]
        }
    }
    __syncthreads();
    float vals[4];
    float mymax = -1e30f;
    #pragma unroll
    for (int e = 0; e < 4; ++e) {
        int kk = t + e * 256;
        float v = 0.f;
        #pragma unroll
        for (int d = 0; d < 3; ++d) {
            int kd = kk + d - 1;
            if (kd >= 0 && kd < L) v += s3[d][kd >> 5][kd & 31];
        }
        v *= 10.0f;               // SCALE
        vals[e] = v;
        mymax = fmaxf(mymax, v);
    }
    red[t] = mymax; __syncthreads();
    for (int s = 128; s > 0; s >>= 1) {
        if (t < s) red[t] = fmaxf(red[t], red[t + s]);
        __syncthreads();
    }
    float Mx = red[0]; __syncthreads();
    float mysum = 0.f;
    #pragma unroll
    for (int e = 0; e < 4; ++e) { vals[e] = __expf(vals[e] - Mx); mysum += vals[e]; }
    red[t] = mysum; __syncthreads();
    for (int s = 128; s > 0; s >>= 1) {
        if (t < s) red[t] += red[t + s];
        __syncthreads();
    }
    float rinv = 1.f / red[0];
    float* Yt = ws + A_OFF + (size_t)n * L * L + (size_t)p * L;   // overwrite A
    #pragma unroll
    for (int e = 0; e < 4; ++e) Yt[t + e * 256] = vals[e] * rinv;
}

// ---------------------------------------------------------------------------
// K5: materialize deconv weights RW[k][(c,u,v)] = b~[c, 2*ly-1+u, 2*lx-1+v],
// zero-padded; k in cm l-order: ly = k&31, lx = k>>5.
__global__ void k5_rw(const float* __restrict__ b, float* __restrict__ ws) {
    int n = blockIdx.y, kk = blockIdx.x, t = threadIdx.x;
    int ly = kk & 31, lx = kk >> 5;
    const float* bp = b + (size_t)n * NC * HF * HF;
    float* RW = ws + RW_OFF + ((size_t)n * L + kk) * MN;
    for (int e = 0; e < 6; ++e) {
        int m = t + e * 256;
        int c = m >> 4, u = (m >> 2) & 3, v = m & 3;
        int r = 2 * ly - 1 + u, s = 2 * lx - 1 + v;
        float val = 0.f;
        if (r >= 0 && r < HF && s >= 0 && s < HF) val = bp[((size_t)c * HF + r) * HF + s];
        RW[m] = val;
    }
}

// ---------------------------------------------------------------------------
// K6: Z[p][m] = sum_k Yt[p][k] * RW[k][m]  (1024x1024 x 1024x1536 per batch),
// epilogue scatters each Z element to its unique output pixel:
// out[c, 2i+u-1, 2j+v-1] += Z/4  (atomicAdd; <=4 sources per pixel).
// 128x128 tile per block, 8x8 micro-tile, K-tile 16.
__global__ __launch_bounds__(256) void k6_mm_scatter(const float* __restrict__ ws,
                                                     float* __restrict__ out) {
    int n = blockIdx.z;
    int m0 = blockIdx.x * 128;
    int p0 = blockIdx.y * 128;
    int t = threadIdx.x;
    int tp = t >> 4, tm = t & 15;
    __shared__ float As[16][132];   // [k][p]
    __shared__ float Bs[16][132];   // [k][m]
    const float* Yt = ws + A_OFF + (size_t)n * L * L;
    const float* RW = ws + RW_OFF + (size_t)n * L * MN;
    float acc[8][8] = {};
    for (int k0 = 0; k0 < L; k0 += 16) {
        #pragma unroll
        for (int e = 0; e < 2; ++e) {
            int idx = t + e * 256;            // 0..511
            int kq = idx & 3, pl = idx >> 2;  // float4 along k
            float4 v = *(const float4*)&Yt[(size_t)(p0 + pl) * L + k0 + kq * 4];
            As[kq * 4 + 0][pl] = v.x;
            As[kq * 4 + 1][pl] = v.y;
            As[kq * 4 + 2][pl] = v.z;
            As[kq * 4 + 3][pl] = v.w;
        }
        #pragma unroll
        for (int e = 0; e < 2; ++e) {
            int idx = t + e * 256;
            int mq = idx & 31, kl = idx >> 5;
            float4 v = *(const float4*)&RW[(size_t)(k0 + kl) * MN + m0 + mq * 4];
            *(float4*)&Bs[kl][mq * 4] = v;
        }
        __syncthreads();
        #pragma unroll
        for (int k = 0; k < 16; ++k) {
            float4 a0 = *(const float4*)&As[k][tp * 8];
            float4 a1 = *(const float4*)&As[k][tp * 8 + 4];
            float4 b0 = *(const float4*)&Bs[k][tm * 8];
            float4 b1 = *(const float4*)&Bs[k][tm * 8 + 4];
            float av[8] = {a0.x, a0.y, a0.z, a0.w, a1.x, a1.y, a1.z, a1.w};
            float bv[8] = {b0.x, b0.y, b0.z, b0.w, b1.x, b1.y, b1.z, b1.w};
            #pragma unroll
            for (int aa = 0; aa < 8; ++aa)
                #pragma unroll
                for (int bb = 0; bb < 8; ++bb)
                    acc[aa][bb] += av[aa] * bv[bb];
        }
        __syncthreads();
    }
    float* outp = out + (size_t)n * NC * HF * HF;
    #pragma unroll
    for (int aa = 0; aa < 8; ++aa) {
        int p = p0 + tp * 8 + aa;
        int i = p >> 5, j = p & 31;
        #pragma unroll
        for (int bb = 0; bb < 8; ++bb) {
            int m = m0 + tm * 8 + bb;
            int c = m >> 4, u = (m >> 2) & 3, v = m & 3;
            int y = 2 * i + u - 1, x = 2 * j + v - 1;
            if (y >= 0 && y < HF && x >= 0 && x < HF)
                atomicAdd(&outp[((size_t)c * HF + y) * HF + x], 0.25f * acc[aa][bb]);
        }
    }
}

// ---------------------------------------------------------------------------
extern "C" void kernel_launch(void* const* d_in, const int* in_sizes, int n_in,
                              void* d_out, int out_size, void* d_ws, size_t ws_size,
                              hipStream_t stream) {
    const float* f = (const float*)d_in[0];
    const float* b = (const float*)d_in[1];
    float* out = (float*)d_out;
    float* ws = (float*)d_ws;

    hipMemsetAsync(d_out, 0, (size_t)out_size * sizeof(float), stream);

    k0_norm<<<NB, 1024, 0, stream>>>(b, ws);
    k1_gram<<<dim3(16, 16, NB), 256, 0, stream>>>(f, b, ws);
    k2_score<<<dim3(1024, NB), 256, 0, stream>>>(ws);
    k3_fuse1t<<<dim3(32, 32, NB), 256, 0, stream>>>(ws);
    k4_fuse2_softmax<<<dim3(1024, NB), 256, 0, stream>>>(ws);
    k5_rw<<<dim3(1024, NB), 256, 0, stream>>>(b, ws);
    k6_mm_scatter<<<dim3(12, 8, NB), 256, 0, stream>>>(ws, out);
}

// Round 3
// 267.166 us; speedup vs baseline: 3.8687x; 3.8687x over previous
//
#include <hip/hip_runtime.h>
#include <math.h>

#define NB 8
#define NC 96
#define HF 64
#define HS 32
#define L 1024
#define MN 1536   // 96 * 16 taps

// workspace layout — all regions disjoint & type-pure during their lifetime:
//  G   (float) : [NB][L][L]   gram, then F1T            bytes [0, 32M)
//  A   (float) : [NB][L][L]   raw scores                bytes [32M, 64M)
//  YB  (bf16)  : [NB][L][L]   softmax probs [p][k]      bytes [64M, 80M)
//  RWT (bf16)  : [NB][MN][L]  deconv weights [m][k]     bytes [80M, 104M)
//  N   (float) : [NB][L]      inv patch norms           bytes [104M, +32K)
//  Z   (float) : [NB][L][MN]  deconv matmul result      bytes [0, 50.3M)
//                (overlays G+A, which are dead after k4 reads F1T)
#define G_OFF   0ull
#define A_OFF   (8ull * 1024 * 1024)            // float offset
#define YB_B    (64ull * 1024 * 1024)           // byte offset
#define RWT_B   (80ull * 1024 * 1024)           // byte offset
#define N_OFF   (27262976ull)                   // float offset (104 MB)
#define Z_OFF   0ull                            // float offset

typedef __attribute__((ext_vector_type(8))) short short8;
typedef __attribute__((ext_vector_type(4))) float float4v;

__device__ inline unsigned short f2bf(float x) {
    union { float f; unsigned u; } v; v.f = x;
    unsigned r = v.u + 0x7fff + ((v.u >> 16) & 1);   // RNE
    return (unsigned short)(r >> 16);
}

// ---------------------------------------------------------------------------
// K0: inv patch norms.
__global__ void k0_norm(const float* __restrict__ b, float* __restrict__ ws) {
    int n = blockIdx.x;
    int t = threadIdx.x;
    int i = t >> 5, j = t & 31;
    __shared__ float sq[1024];
    const float* bp = b + (size_t)n * NC * HF * HF;
    float s = 0.f;
    for (int c = 0; c < NC; ++c) {
        float v = bp[((size_t)c * HF + 2 * i) * HF + 2 * j];
        s += v * v;
    }
    sq[t] = s;
    __syncthreads();
    float nsq = 0.f;
    #pragma unroll
    for (int dy = -1; dy <= 1; ++dy)
        #pragma unroll
        for (int dx = -1; dx <= 1; ++dx) {
            int ii = i + dy, jj = j + dx;
            if (ii >= 0 && ii < HS && jj >= 0 && jj < HS) nsq += sq[ii * HS + jj];
        }
    ws[N_OFF + (size_t)n * L + t] = 1.f / fmaxf(sqrtf(nsq), 1e-4f);
}

// ---------------------------------------------------------------------------
// K1: Gram matrix G[l][p] = sum_c bs[c,l] * fs[c,p].  fp32 (precision-critical).
__global__ __launch_bounds__(256) void k1_gram(const float* __restrict__ f,
                                               const float* __restrict__ b,
                                               float* __restrict__ ws) {
    int n = blockIdx.z;
    int l0 = blockIdx.y * 64, p0 = blockIdx.x * 64;
    int t = threadIdx.x;
    int tp = t >> 4, tm = t & 15;
    __shared__ float Bt[32][68];
    __shared__ float Ft[32][68];
    float acc[4][4] = {};
    const float* bp = b + (size_t)n * NC * HF * HF;
    const float* fp = f + (size_t)n * NC * HF * HF;
    int ly0 = l0 >> 5;
    int py0 = p0 >> 5;
    for (int c0 = 0; c0 < NC; c0 += 32) {
        #pragma unroll
        for (int e = 0; e < 8; ++e) {
            int idx = t + e * 256;
            int q = idx & 63, cl = idx >> 6;
            int c = c0 + cl;
            Bt[cl][q] = bp[((size_t)c * HF + 2 * (ly0 + (q >> 5))) * HF + 2 * (q & 31)];
            Ft[cl][q] = fp[((size_t)c * HF + 2 * (py0 + (q >> 5))) * HF + 2 * (q & 31)];
        }
        __syncthreads();
        for (int cl = 0; cl < 32; ++cl) {
            float4 a4 = *(const float4*)&Bt[cl][tp * 4];
            float4 b4 = *(const float4*)&Ft[cl][tm * 4];
            float av[4] = {a4.x, a4.y, a4.z, a4.w};
            float bv[4] = {b4.x, b4.y, b4.z, b4.w};
            #pragma unroll
            for (int aa = 0; aa < 4; ++aa)
                #pragma unroll
                for (int bb = 0; bb < 4; ++bb)
                    acc[aa][bb] += av[aa] * bv[bb];
        }
        __syncthreads();
    }
    float* G = ws + G_OFF + (size_t)n * L * L;
    #pragma unroll
    for (int aa = 0; aa < 4; ++aa) {
        int l = l0 + tp * 4 + aa;
        float4 v = make_float4(acc[aa][0], acc[aa][1], acc[aa][2], acc[aa][3]);
        *(float4*)&G[(size_t)l * L + p0 + tm * 4] = v;
    }
}

// ---------------------------------------------------------------------------
// K2: raw scores via 9-shift Gram sum + norm.
__global__ void k2_score(float* __restrict__ ws) {
    int n = blockIdx.y, l = blockIdx.x, t = threadIdx.x;
    int ly = l >> 5, lx = l & 31;
    const float* G = ws + G_OFF + (size_t)n * L * L;
    float invn = ws[N_OFF + (size_t)n * L + l];
    float* A = ws + A_OFF + (size_t)n * L * L + (size_t)l * L;
    for (int e = 0; e < 4; ++e) {
        int p = t + e * 256;
        int py = p >> 5, px = p & 31;
        float s = 0.f;
        #pragma unroll
        for (int dy = -1; dy <= 1; ++dy) {
            int lyy = ly + dy;
            int pyy = py + dy;
            if (lyy < 0 || lyy >= HS) continue;
            #pragma unroll
            for (int dx = -1; dx <= 1; ++dx) {
                int lxx = lx + dx;
                int pxx = px + dx;
                if (lxx >= 0 && lxx < HS && pyy >= 0 && pyy < HS && pxx >= 0 && pxx < HS)
                    s += G[(size_t)(lyy * HS + lxx) * L + pyy * HS + pxx];
            }
        }
        A[p] = invn * s;
    }
}

// ---------------------------------------------------------------------------
// K3: first fuse (3-tap diagonal, row-major flat) + transpose into G region.
__global__ void k3_fuse1t(float* __restrict__ ws) {
    int n = blockIdx.z;
    int i0 = blockIdx.y * 32, j0 = blockIdx.x * 32;
    int t = threadIdx.x;
    __shared__ float sA[34][35];
    const float* A = ws + A_OFF + (size_t)n * L * L;
    for (int e = 0; e < 5; ++e) {
        int idx = t + e * 256;
        if (idx < 34 * 34) {
            int a = idx / 34, bq = idx % 34;
            int gi = i0 - 1 + a, gj = j0 - 1 + bq;
            float v = 0.f;
            if (gi >= 0 && gi < L && gj >= 0 && gj < L) v = A[(size_t)gi * L + gj];
            sA[a][bq] = v;
        }
    }
    __syncthreads();
    float* F1T = ws + G_OFF + (size_t)n * L * L;
    #pragma unroll
    for (int e = 0; e < 4; ++e) {
        int idx = t + e * 256;
        int jl = idx >> 5, il = idx & 31;
        float v = sA[il][jl] + sA[il + 1][jl + 1] + sA[il + 2][jl + 2];
        F1T[(size_t)(j0 + jl) * L + i0 + il] = v;
    }
}

// ---------------------------------------------------------------------------
// K4: second fuse (cm-flat diagonal 3-tap) + softmax over l; write bf16
// Yb[p][k] (k in cm l-order) into the dedicated YB region.
__global__ void k4_fuse2_softmax(float* __restrict__ ws) {
    int n = blockIdx.y, p = blockIdx.x, t = threadIdx.x;
    int py = p >> 5, px = p & 31;
    int Jc = px * HS + py;
    __shared__ float s3[3][32][33];
    __shared__ float red[256];
    const float* F1T = ws + G_OFF + (size_t)n * L * L;
    #pragma unroll
    for (int d = 0; d < 3; ++d) {
        int Jd = Jc + d - 1;
        bool ok = (Jd >= 0 && Jd < L);
        int rd = ok ? ((Jd & 31) * HS + (Jd >> 5)) : 0;
        const float* row = F1T + (size_t)rd * L;
        for (int e = 0; e < 4; ++e) {
            int i_ = t + e * 256;
            float v = ok ? row[i_] : 0.f;
            s3[d][i_ & 31][i_ >> 5] = v;
        }
    }
    __syncthreads();
    float vals[4];
    float mymax = -1e30f;
    #pragma unroll
    for (int e = 0; e < 4; ++e) {
        int kk = t + e * 256;
        float v = 0.f;
        #pragma unroll
        for (int d = 0; d < 3; ++d) {
            int kd = kk + d - 1;
            if (kd >= 0 && kd < L) v += s3[d][kd >> 5][kd & 31];
        }
        v *= 10.0f;
        vals[e] = v;
        mymax = fmaxf(mymax, v);
    }
    red[t] = mymax; __syncthreads();
    for (int s = 128; s > 0; s >>= 1) {
        if (t < s) red[t] = fmaxf(red[t], red[t + s]);
        __syncthreads();
    }
    float Mx = red[0]; __syncthreads();
    float mysum = 0.f;
    #pragma unroll
    for (int e = 0; e < 4; ++e) { vals[e] = __expf(vals[e] - Mx); mysum += vals[e]; }
    red[t] = mysum; __syncthreads();
    for (int s = 128; s > 0; s >>= 1) {
        if (t < s) red[t] += red[t + s];
        __syncthreads();
    }
    float rinv = 1.f / red[0];
    unsigned short* Yb = (unsigned short*)((char*)ws + YB_B) + (size_t)n * L * L + (size_t)p * L;
    #pragma unroll
    for (int e = 0; e < 4; ++e) Yb[t + e * 256] = f2bf(vals[e] * rinv);
}

// ---------------------------------------------------------------------------
// K5: transposed bf16 deconv weights RWt[m][k], m = c*16+u*4+v, k cm l-order.
__global__ void k5_rwt(const float* __restrict__ b, float* __restrict__ ws) {
    int c = blockIdx.x, n = blockIdx.y;
    int t = threadIdx.x;
    __shared__ float pl[64][65];
    const float* bp = b + ((size_t)n * NC + c) * (HF * HF);
    for (int e = 0; e < 16; ++e) {
        int idx = t + e * 256;
        pl[idx >> 6][idx & 63] = bp[idx];
    }
    __syncthreads();
    unsigned short* RWt = (unsigned short*)((char*)ws + RWT_B) + ((size_t)n * MN + c * 16) * L;
    #pragma unroll
    for (int uv = 0; uv < 16; ++uv) {
        int u = uv >> 2, v = uv & 3;
        for (int e = 0; e < 4; ++e) {
            int k = t + e * 256;
            int ly = k & 31, lx = k >> 5;
            int r = 2 * ly - 1 + u, s = 2 * lx - 1 + v;
            float val = (r >= 0 && r < HF && s >= 0 && s < HF) ? pl[r][s] : 0.f;
            RWt[(size_t)uv * L + k] = f2bf(val);
        }
    }
}

// ---------------------------------------------------------------------------
// K6: Z[p][m] = sum_k Yb[p][k] * RWt[m][k] via bf16 MFMA 16x16x32.
// 128x128 block tile, 4 waves, 64x64 wave tile (4x4 MFMAs), BK=64.
// Plain fp32 stores to Z (overlays dead G/A region) — no atomics.
__global__ __launch_bounds__(256) void k6_mfma_z(float* __restrict__ ws) {
    int n = blockIdx.z;
    int m0 = blockIdx.x * 128;
    int p0 = blockIdx.y * 128;
    int t = threadIdx.x;
    int lane = t & 63, wv = t >> 6;
    int wp = (wv >> 1) * 64, wm = (wv & 1) * 64;
    int fr = lane & 15, qd = lane >> 4;

    __shared__ unsigned short As[128][72];
    __shared__ unsigned short Bs[128][72];

    const unsigned short* Ybp = (const unsigned short*)((const char*)ws + YB_B) + (size_t)n * L * L;
    const unsigned short* RWtp = (const unsigned short*)((const char*)ws + RWT_B) + (size_t)n * MN * L;

    float4v acc[4][4] = {};

    for (int k0 = 0; k0 < L; k0 += 64) {
        __syncthreads();
        #pragma unroll
        for (int e = 0; e < 4; ++e) {
            int id = t + e * 256;
            int row = id >> 3, cb = id & 7;
            *(short8*)&As[row][cb * 8] =
                *(const short8*)(Ybp + (size_t)(p0 + row) * L + k0 + cb * 8);
            *(short8*)&Bs[row][cb * 8] =
                *(const short8*)(RWtp + (size_t)(m0 + row) * L + k0 + cb * 8);
        }
        __syncthreads();
        #pragma unroll
        for (int ks = 0; ks < 2; ++ks) {
            short8 af[4], bf[4];
            #pragma unroll
            for (int a = 0; a < 4; ++a)
                af[a] = *(const short8*)&As[wp + a * 16 + fr][ks * 32 + qd * 8];
            #pragma unroll
            for (int bq = 0; bq < 4; ++bq)
                bf[bq] = *(const short8*)&Bs[wm + bq * 16 + fr][ks * 32 + qd * 8];
            #pragma unroll
            for (int a = 0; a < 4; ++a)
                #pragma unroll
                for (int bq = 0; bq < 4; ++bq)
                    acc[a][bq] = __builtin_amdgcn_mfma_f32_16x16x32_bf16(
                        af[a], bf[bq], acc[a][bq], 0, 0, 0);
        }
    }

    float* Zp = ws + Z_OFF + (size_t)n * L * MN;
    #pragma unroll
    for (int a = 0; a < 4; ++a) {
        #pragma unroll
        for (int r = 0; r < 4; ++r) {
            int p = p0 + wp + a * 16 + qd * 4 + r;
            #pragma unroll
            for (int bq = 0; bq < 4; ++bq) {
                int m = m0 + wm + bq * 16 + fr;
                Zp[(size_t)p * MN + m] = acc[a][bq][r];
            }
        }
    }
}

// ---------------------------------------------------------------------------
// K7: deterministic gather epilogue — each output pixel reads its <=4 Z
// entries (staged via LDS) and does one plain store.  out fully overwritten.
// Block = (n, c, y-quad): stages Z[p in 4 i-rows x 32 j][c*16 .. +16).
__global__ __launch_bounds__(256) void k7_gather(const float* __restrict__ ws,
                                                 float* __restrict__ out) {
    int yq = blockIdx.x, c = blockIdx.y, n = blockIdx.z;
    int t = threadIdx.x;
    int y0 = yq * 4;
    int ibase = (y0 >> 1) - 1;
    __shared__ float zs[128][17];
    const float* Zp = ws + Z_OFF + (size_t)n * L * MN;
    #pragma unroll
    for (int e = 0; e < 2; ++e) {
        int idx = t + e * 256;          // [0,512)
        int pl = idx >> 2, q = idx & 3;
        int il = pl >> 5, j = pl & 31;
        int i = ibase + il;
        float4 v = make_float4(0.f, 0.f, 0.f, 0.f);
        if (i >= 0 && i < HS)
            v = *(const float4*)&Zp[(size_t)(i * HS + j) * MN + c * 16 + q * 4];
        zs[pl][q * 4 + 0] = v.x;
        zs[pl][q * 4 + 1] = v.y;
        zs[pl][q * 4 + 2] = v.z;
        zs[pl][q * 4 + 3] = v.w;
    }
    __syncthreads();
    int y = y0 + (t >> 6), x = t & 63;
    int ih = (y + 1) >> 1, jh = (x + 1) >> 1;
    float s = 0.f;
    #pragma unroll
    for (int di = 0; di < 2; ++di) {
        int i = ih - di;
        if (i < 0 || i >= HS) continue;
        int u = y + 1 - 2 * i;          // in [0,4) by construction
        int il = i - ibase;             // in [0,4)
        #pragma unroll
        for (int dj = 0; dj < 2; ++dj) {
            int j = jh - dj;
            if (j < 0 || j >= HS) continue;
            int v = x + 1 - 2 * j;
            s += zs[il * 32 + j][u * 4 + v];
        }
    }
    out[(((size_t)n * NC + c) * HF + y) * HF + x] = 0.25f * s;
}

// ---------------------------------------------------------------------------
extern "C" void kernel_launch(void* const* d_in, const int* in_sizes, int n_in,
                              void* d_out, int out_size, void* d_ws, size_t ws_size,
                              hipStream_t stream) {
    const float* f = (const float*)d_in[0];
    const float* b = (const float*)d_in[1];
    float* out = (float*)d_out;
    float* ws = (float*)d_ws;

    k0_norm<<<NB, 1024, 0, stream>>>(b, ws);
    k1_gram<<<dim3(16, 16, NB), 256, 0, stream>>>(f, b, ws);
    k2_score<<<dim3(1024, NB), 256, 0, stream>>>(ws);
    k3_fuse1t<<<dim3(32, 32, NB), 256, 0, stream>>>(ws);
    k4_fuse2_softmax<<<dim3(1024, NB), 256, 0, stream>>>(ws);
    k5_rwt<<<dim3(NC, NB), 256, 0, stream>>>(b, ws);
    k6_mfma_z<<<dim3(12, 8, NB), 256, 0, stream>>>(ws);
    k7_gather<<<dim3(16, NC, NB), 256, 0, stream>>>(ws, out);
}

// Round 4
// 267.064 us; speedup vs baseline: 3.8702x; 1.0004x over previous
//
#include <hip/hip_runtime.h>
#include <math.h>

#define NB 8
#define NC 96
#define HF 64
#define HS 32
#define L 1024
#define MN 1536   // 96 * 16 taps

// workspace layout — all regions disjoint & type-pure during their lifetime:
//  G   (float) : [NB][L][L]   gram                       bytes [0, 32M)
//  F1T (float) : [NB][L][L]   fused+transposed scores    bytes [32M, 64M)
//  YB  (bf16)  : [NB][L][L]   softmax probs [p][k]       bytes [64M, 80M)
//  RWT (bf16)  : [NB][MN][L]  deconv weights [m][k]      bytes [80M, 104M)
//  N   (float) : [NB][L]      inv patch norms            @104M
//  SQP (float) : [NB][12][L]  partial sq sums            @104M+32K
//  Z   (float) : [NB][L][MN]  deconv matmul result       bytes [0, 50.3M)
//                (overlays G+F1T, both dead before k6)
#define G_OFF    0ull
#define F1T_OFF  (8ull * 1024 * 1024)           // float offset
#define YB_B     (64ull * 1024 * 1024)          // byte offset
#define RWT_B    (80ull * 1024 * 1024)          // byte offset
#define N_OFF    (27262976ull)                  // float offset (104 MB)
#define SQP_OFF  (27271168ull)                  // float offset
#define Z_OFF    0ull                           // float offset

typedef __attribute__((ext_vector_type(8))) short short8;
typedef __attribute__((ext_vector_type(4))) float float4v;

__device__ inline unsigned short f2bf(float x) {
    union { float f; unsigned u; } v; v.f = x;
    unsigned r = v.u + 0x7fff + ((v.u >> 16) & 1);   // RNE
    return (unsigned short)(r >> 16);
}

// ---------------------------------------------------------------------------
// K0a: partial channel sums of bs^2.  Block (cg, n): 8 channels, 1024 pos.
__global__ void k0a_sqpart(const float* __restrict__ b, float* __restrict__ ws) {
    int cg = blockIdx.x, n = blockIdx.y;
    int t = threadIdx.x;
    int i = t >> 5, j = t & 31;
    const float* bp = b + ((size_t)n * NC + cg * 8) * (HF * HF);
    float s = 0.f;
    #pragma unroll
    for (int c = 0; c < 8; ++c) {
        float v = bp[(size_t)c * HF * HF + (2 * i) * HF + 2 * j];
        s += v * v;
    }
    ws[SQP_OFF + ((size_t)n * 12 + cg) * L + t] = s;
}

// K0b: finalize — sum partials, 3x3 neighborhood, inv norm.
__global__ void k0b_norm(float* __restrict__ ws) {
    int n = blockIdx.x;
    int t = threadIdx.x;
    int i = t >> 5, j = t & 31;
    __shared__ float sq[1024];
    float s = 0.f;
    #pragma unroll
    for (int cg = 0; cg < 12; ++cg)
        s += ws[SQP_OFF + ((size_t)n * 12 + cg) * L + t];
    sq[t] = s;
    __syncthreads();
    float nsq = 0.f;
    #pragma unroll
    for (int dy = -1; dy <= 1; ++dy)
        #pragma unroll
        for (int dx = -1; dx <= 1; ++dx) {
            int ii = i + dy, jj = j + dx;
            if (ii >= 0 && ii < HS && jj >= 0 && jj < HS) nsq += sq[ii * HS + jj];
        }
    ws[N_OFF + (size_t)n * L + t] = 1.f / fmaxf(sqrtf(nsq), 1e-4f);
}

// ---------------------------------------------------------------------------
// K1: Gram matrix G[l][p] = sum_c bs[c,l] * fs[c,p].  fp32, 128x128 tile,
// 8x8 micro-tile (64 FMA per 4 LDS b128 reads).
__global__ __launch_bounds__(256) void k1_gram(const float* __restrict__ f,
                                               const float* __restrict__ b,
                                               float* __restrict__ ws) {
    int n = blockIdx.z;
    int l0 = blockIdx.y * 128, p0 = blockIdx.x * 128;
    int t = threadIdx.x;
    int tp = t >> 4, tm = t & 15;
    __shared__ float Bt[32][132];
    __shared__ float Ft[32][132];
    float acc[8][8] = {};
    const float* bp = b + (size_t)n * NC * HF * HF;
    const float* fp = f + (size_t)n * NC * HF * HF;
    int ly0 = l0 >> 5;
    int py0 = p0 >> 5;
    for (int c0 = 0; c0 < NC; c0 += 32) {
        #pragma unroll
        for (int e = 0; e < 16; ++e) {
            int idx = t + e * 256;          // 0..4095
            int q = idx & 127, cl = idx >> 7;
            int c = c0 + cl;
            Bt[cl][q] = bp[((size_t)c * HF + 2 * (ly0 + (q >> 5))) * HF + 2 * (q & 31)];
            Ft[cl][q] = fp[((size_t)c * HF + 2 * (py0 + (q >> 5))) * HF + 2 * (q & 31)];
        }
        __syncthreads();
        for (int cl = 0; cl < 32; ++cl) {
            float4 a0 = *(const float4*)&Bt[cl][tp * 8];
            float4 a1 = *(const float4*)&Bt[cl][tp * 8 + 4];
            float4 b0 = *(const float4*)&Ft[cl][tm * 8];
            float4 b1 = *(const float4*)&Ft[cl][tm * 8 + 4];
            float av[8] = {a0.x, a0.y, a0.z, a0.w, a1.x, a1.y, a1.z, a1.w};
            float bv[8] = {b0.x, b0.y, b0.z, b0.w, b1.x, b1.y, b1.z, b1.w};
            #pragma unroll
            for (int aa = 0; aa < 8; ++aa)
                #pragma unroll
                for (int bb = 0; bb < 8; ++bb)
                    acc[aa][bb] += av[aa] * bv[bb];
        }
        __syncthreads();
    }
    float* G = ws + G_OFF + (size_t)n * L * L;
    #pragma unroll
    for (int aa = 0; aa < 8; ++aa) {
        int l = l0 + tp * 8 + aa;
        *(float4*)&G[(size_t)l * L + p0 + tm * 8] =
            make_float4(acc[aa][0], acc[aa][1], acc[aa][2], acc[aa][3]);
        *(float4*)&G[(size_t)l * L + p0 + tm * 8 + 4] =
            make_float4(acc[aa][4], acc[aa][5], acc[aa][6], acc[aa][7]);
    }
}

// ---------------------------------------------------------------------------
// K23: fused score + first fuse + transpose.
// A[l][p] = invn[l] * sum_{9 masked diag taps s} G[l+s][p+s]  (computed into
// a 34x34 LDS halo), then F1T[j][i] = sum_d A[i+d][j+d], stored transposed
// into the F1T region.  A is never materialized in global memory.
__global__ __launch_bounds__(256) void k23_score_fuse1t(float* __restrict__ ws) {
    int n = blockIdx.z;
    int i0 = blockIdx.y * 32, j0 = blockIdx.x * 32;
    int t = threadIdx.x;
    __shared__ float sA[34][35];
    const float* G = ws + G_OFF + (size_t)n * L * L;
    const float* invn = ws + N_OFF + (size_t)n * L;
    for (int e = 0; e < 5; ++e) {
        int idx = t + e * 256;
        if (idx < 34 * 34) {
            int ih = idx / 34, jh = idx % 34;
            int l = i0 - 1 + ih, p = j0 - 1 + jh;
            float a = 0.f;
            if (l >= 0 && l < L && p >= 0 && p < L) {
                int ly = l >> 5, lx = l & 31, py = p >> 5, px = p & 31;
                float s = 0.f;
                #pragma unroll
                for (int dy = -1; dy <= 1; ++dy) {
                    if (ly + dy < 0 || ly + dy >= HS || py + dy < 0 || py + dy >= HS) continue;
                    #pragma unroll
                    for (int dx = -1; dx <= 1; ++dx) {
                        if (lx + dx < 0 || lx + dx >= HS || px + dx < 0 || px + dx >= HS) continue;
                        int sh = dy * HS + dx;
                        s += G[(size_t)(l + sh) * L + p + sh];
                    }
                }
                a = invn[l] * s;
            }
            sA[ih][jh] = a;
        }
    }
    __syncthreads();
    float* F1T = ws + F1T_OFF + (size_t)n * L * L;
    #pragma unroll
    for (int e = 0; e < 4; ++e) {
        int idx = t + e * 256;
        int jl = idx >> 5, il = idx & 31;
        float v = sA[il][jl] + sA[il + 1][jl + 1] + sA[il + 2][jl + 2];
        F1T[(size_t)(j0 + jl) * L + i0 + il] = v;
    }
}

// ---------------------------------------------------------------------------
// K4: second fuse (cm-flat diag 3-tap) + softmax over l; write bf16 Yb[p][k].
// Wave-shuffle reductions (2 barriers).
__global__ void k4_fuse2_softmax(float* __restrict__ ws) {
    int n = blockIdx.y, p = blockIdx.x, t = threadIdx.x;
    int py = p >> 5, px = p & 31;
    int Jc = px * HS + py;
    __shared__ float s3[3][32][33];
    __shared__ float red[8];
    const float* F1T = ws + F1T_OFF + (size_t)n * L * L;
    #pragma unroll
    for (int d = 0; d < 3; ++d) {
        int Jd = Jc + d - 1;
        bool ok = (Jd >= 0 && Jd < L);
        int rd = ok ? ((Jd & 31) * HS + (Jd >> 5)) : 0;
        const float* row = F1T + (size_t)rd * L;
        for (int e = 0; e < 4; ++e) {
            int i_ = t + e * 256;
            float v = ok ? row[i_] : 0.f;
            s3[d][i_ & 31][i_ >> 5] = v;
        }
    }
    __syncthreads();
    float vals[4];
    float mymax = -1e30f;
    #pragma unroll
    for (int e = 0; e < 4; ++e) {
        int kk = t + e * 256;
        float v = 0.f;
        #pragma unroll
        for (int d = 0; d < 3; ++d) {
            int kd = kk + d - 1;
            if (kd >= 0 && kd < L) v += s3[d][kd >> 5][kd & 31];
        }
        v *= 10.0f;
        vals[e] = v;
        mymax = fmaxf(mymax, v);
    }
    #pragma unroll
    for (int off = 32; off > 0; off >>= 1)
        mymax = fmaxf(mymax, __shfl_xor(mymax, off));
    if ((t & 63) == 0) red[t >> 6] = mymax;
    __syncthreads();
    float Mx = fmaxf(fmaxf(red[0], red[1]), fmaxf(red[2], red[3]));
    float mysum = 0.f;
    #pragma unroll
    for (int e = 0; e < 4; ++e) { vals[e] = __expf(vals[e] - Mx); mysum += vals[e]; }
    #pragma unroll
    for (int off = 32; off > 0; off >>= 1)
        mysum += __shfl_xor(mysum, off);
    if ((t & 63) == 0) red[4 + (t >> 6)] = mysum;
    __syncthreads();
    float rinv = 1.f / (red[4] + red[5] + red[6] + red[7]);
    unsigned short* Yb = (unsigned short*)((char*)ws + YB_B) + (size_t)n * L * L + (size_t)p * L;
    #pragma unroll
    for (int e = 0; e < 4; ++e) Yb[t + e * 256] = f2bf(vals[e] * rinv);
}

// ---------------------------------------------------------------------------
// K5: transposed bf16 deconv weights RWt[m][k], m = c*16+u*4+v, k cm l-order.
__global__ void k5_rwt(const float* __restrict__ b, float* __restrict__ ws) {
    int c = blockIdx.x, n = blockIdx.y;
    int t = threadIdx.x;
    __shared__ float pl[64][65];
    const float* bp = b + ((size_t)n * NC + c) * (HF * HF);
    for (int e = 0; e < 16; ++e) {
        int idx = t + e * 256;
        pl[idx >> 6][idx & 63] = bp[idx];
    }
    __syncthreads();
    unsigned short* RWt = (unsigned short*)((char*)ws + RWT_B) + ((size_t)n * MN + c * 16) * L;
    #pragma unroll
    for (int uv = 0; uv < 16; ++uv) {
        int u = uv >> 2, v = uv & 3;
        for (int e = 0; e < 4; ++e) {
            int k = t + e * 256;
            int ly = k & 31, lx = k >> 5;
            int r = 2 * ly - 1 + u, s = 2 * lx - 1 + v;
            float val = (r >= 0 && r < HF && s >= 0 && s < HF) ? pl[r][s] : 0.f;
            RWt[(size_t)uv * L + k] = f2bf(val);
        }
    }
}

// ---------------------------------------------------------------------------
// K6: Z[p][m] = sum_k Yb[p][k] * RWt[m][k] via bf16 MFMA 16x16x32.
// XCD-swizzled: each XCD owns one batch n, so RWt(n) (3 MB) stays resident
// in its 4 MB L2 while Yb streams through.
__global__ __launch_bounds__(256) void k6_mfma_z(float* __restrict__ ws) {
    int bid = blockIdx.x + 12 * (blockIdx.y + 8 * blockIdx.z);   // 0..767
    int w = (bid & 7) * 96 + (bid >> 3);
    int mt = w % 12;
    int g = w / 12;                  // 0..63
    int n = g >> 3;
    int m0 = mt * 128;
    int p0 = (g & 7) * 128;
    int t = threadIdx.x;
    int lane = t & 63, wv = t >> 6;
    int wp = (wv >> 1) * 64, wm = (wv & 1) * 64;
    int fr = lane & 15, qd = lane >> 4;

    __shared__ unsigned short As[128][72];
    __shared__ unsigned short Bs[128][72];

    const unsigned short* Ybp = (const unsigned short*)((const char*)ws + YB_B) + (size_t)n * L * L;
    const unsigned short* RWtp = (const unsigned short*)((const char*)ws + RWT_B) + (size_t)n * MN * L;

    float4v acc[4][4] = {};

    for (int k0 = 0; k0 < L; k0 += 64) {
        __syncthreads();
        #pragma unroll
        for (int e = 0; e < 4; ++e) {
            int id = t + e * 256;
            int row = id >> 3, cb = id & 7;
            *(short8*)&As[row][cb * 8] =
                *(const short8*)(Ybp + (size_t)(p0 + row) * L + k0 + cb * 8);
            *(short8*)&Bs[row][cb * 8] =
                *(const short8*)(RWtp + (size_t)(m0 + row) * L + k0 + cb * 8);
        }
        __syncthreads();
        #pragma unroll
        for (int ks = 0; ks < 2; ++ks) {
            short8 af[4], bf[4];
            #pragma unroll
            for (int a = 0; a < 4; ++a)
                af[a] = *(const short8*)&As[wp + a * 16 + fr][ks * 32 + qd * 8];
            #pragma unroll
            for (int bq = 0; bq < 4; ++bq)
                bf[bq] = *(const short8*)&Bs[wm + bq * 16 + fr][ks * 32 + qd * 8];
            #pragma unroll
            for (int a = 0; a < 4; ++a)
                #pragma unroll
                for (int bq = 0; bq < 4; ++bq)
                    acc[a][bq] = __builtin_amdgcn_mfma_f32_16x16x32_bf16(
                        af[a], bf[bq], acc[a][bq], 0, 0, 0);
        }
    }

    float* Zp = ws + Z_OFF + (size_t)n * L * MN;
    #pragma unroll
    for (int a = 0; a < 4; ++a) {
        #pragma unroll
        for (int r = 0; r < 4; ++r) {
            int p = p0 + wp + a * 16 + qd * 4 + r;
            #pragma unroll
            for (int bq = 0; bq < 4; ++bq) {
                int m = m0 + wm + bq * 16 + fr;
                Zp[(size_t)p * MN + m] = acc[a][bq][r];
            }
        }
    }
}

// ---------------------------------------------------------------------------
// K7: deterministic gather epilogue — each output pixel reads its <=4 Z
// entries (staged via LDS) and does one plain store.
__global__ __launch_bounds__(256) void k7_gather(const float* __restrict__ ws,
                                                 float* __restrict__ out) {
    int yq = blockIdx.x, c = blockIdx.y, n = blockIdx.z;
    int t = threadIdx.x;
    int y0 = yq * 4;
    int ibase = (y0 >> 1) - 1;
    __shared__ float zs[128][17];
    const float* Zp = ws + Z_OFF + (size_t)n * L * MN;
    #pragma unroll
    for (int e = 0; e < 2; ++e) {
        int idx = t + e * 256;
        int pl = idx >> 2, q = idx & 3;
        int il = pl >> 5, j = pl & 31;
        int i = ibase + il;
        float4 v = make_float4(0.f, 0.f, 0.f, 0.f);
        if (i >= 0 && i < HS)
            v = *(const float4*)&Zp[(size_t)(i * HS + j) * MN + c * 16 + q * 4];
        zs[pl][q * 4 + 0] = v.x;
        zs[pl][q * 4 + 1] = v.y;
        zs[pl][q * 4 + 2] = v.z;
        zs[pl][q * 4 + 3] = v.w;
    }
    __syncthreads();
    int y = y0 + (t >> 6), x = t & 63;
    int ih = (y + 1) >> 1, jh = (x + 1) >> 1;
    float s = 0.f;
    #pragma unroll
    for (int di = 0; di < 2; ++di) {
        int i = ih - di;
        if (i < 0 || i >= HS) continue;
        int u = y + 1 - 2 * i;
        int il = i - ibase;
        #pragma unroll
        for (int dj = 0; dj < 2; ++dj) {
            int j = jh - dj;
            if (j < 0 || j >= HS) continue;
            int v = x + 1 - 2 * j;
            s += zs[il * 32 + j][u * 4 + v];
        }
    }
    out[(((size_t)n * NC + c) * HF + y) * HF + x] = 0.25f * s;
}

// ---------------------------------------------------------------------------
extern "C" void kernel_launch(void* const* d_in, const int* in_sizes, int n_in,
                              void* d_out, int out_size, void* d_ws, size_t ws_size,
                              hipStream_t stream) {
    const float* f = (const float*)d_in[0];
    const float* b = (const float*)d_in[1];
    float* out = (float*)d_out;
    float* ws = (float*)d_ws;

    k0a_sqpart<<<dim3(12, NB), 1024, 0, stream>>>(b, ws);
    k0b_norm<<<NB, 1024, 0, stream>>>(ws);
    k1_gram<<<dim3(8, 8, NB), 256, 0, stream>>>(f, b, ws);
    k23_score_fuse1t<<<dim3(32, 32, NB), 256, 0, stream>>>(ws);
    k4_fuse2_softmax<<<dim3(1024, NB), 256, 0, stream>>>(ws);
    k5_rwt<<<dim3(NC, NB), 256, 0, stream>>>(b, ws);
    k6_mfma_z<<<dim3(12, 8, NB), 256, 0, stream>>>(ws);
    k7_gather<<<dim3(16, NC, NB), 256, 0, stream>>>(ws, out);
}

// Round 5
// 248.620 us; speedup vs baseline: 4.1573x; 1.0742x over previous
//
#include <hip/hip_runtime.h>
#include <math.h>

#define NB 8
#define NC 96
#define HF 64
#define HS 32
#define L 1024
#define MN 1536   // 96 * 16 taps

// workspace layout — all regions disjoint & type-pure during their lifetime:
//  G   (float) : [NB][L][L]   gram                       bytes [0, 32M)
//  F1T (float) : [NB][L][L]   fused+transposed scores    bytes [32M, 64M)
//  YB  (bf16)  : [NB][L][L]   softmax probs [p][k]       bytes [64M, 80M)
//  RWT (bf16)  : [NB][MN][L]  deconv weights [m][k]      bytes [80M, 104M)
//  N   (float) : [NB][L]      inv patch norms            @104M
//  FS  (float) : [NB][NC][1024] packed f[::2,::2]        @104M+32K
//  BS  (float) : [NB][NC][1024] packed b[::2,::2]        after FS
//  Z   (float) : [NB][L][MN]  deconv matmul result       bytes [0, 50.3M)
//                (overlays G+F1T, both dead before k6)
#define G_OFF    0ull
#define F1T_OFF  (8ull * 1024 * 1024)           // float offset
#define YB_B     (64ull * 1024 * 1024)          // byte offset
#define RWT_B    (80ull * 1024 * 1024)          // byte offset
#define N_OFF    (27262976ull)                  // float offset (104 MB)
#define FS_OFF   (27271168ull)                  // float offset
#define BS_OFF   (28057600ull)                  // float offset
#define Z_OFF    0ull                           // float offset
// end = 28,844,032 floats = 115.4 MB

typedef __attribute__((ext_vector_type(8))) short short8;
typedef __attribute__((ext_vector_type(4))) float float4v;

__device__ inline unsigned short f2bf(float x) {
    union { float f; unsigned u; } v; v.f = x;
    unsigned r = v.u + 0x7fff + ((v.u >> 16) & 1);   // RNE
    return (unsigned short)(r >> 16);
}

// ---------------------------------------------------------------------------
// KPRE: extract the ::2,::2 subsampled planes of f and b into packed buffers.
__global__ void kpre_pack(const float* __restrict__ f, const float* __restrict__ b,
                          float* __restrict__ ws) {
    int c = blockIdx.x, which = blockIdx.y, n = blockIdx.z;
    const float* src = (which ? b : f) + ((size_t)n * NC + c) * (HF * HF);
    float* dst = ws + (which ? BS_OFF : FS_OFF) + ((size_t)n * NC + c) * 1024;
    int t = threadIdx.x;
    #pragma unroll
    for (int e = 0; e < 4; ++e) {
        int pos = t + e * 256;
        int i = pos >> 5, j = pos & 31;
        dst[pos] = src[(2 * i) * HF + 2 * j];
    }
}

// ---------------------------------------------------------------------------
// K0: inv patch norms from packed bs.
__global__ void k0_norm(float* __restrict__ ws) {
    int n = blockIdx.x;
    int t = threadIdx.x;
    int i = t >> 5, j = t & 31;
    __shared__ float sq[1024];
    const float* bsp = ws + BS_OFF + (size_t)n * NC * 1024;
    float s = 0.f;
    for (int c = 0; c < NC; ++c) {
        float v = bsp[(size_t)c * 1024 + t];
        s += v * v;
    }
    sq[t] = s;
    __syncthreads();
    float nsq = 0.f;
    #pragma unroll
    for (int dy = -1; dy <= 1; ++dy)
        #pragma unroll
        for (int dx = -1; dx <= 1; ++dx) {
            int ii = i + dy, jj = j + dx;
            if (ii >= 0 && ii < HS && jj >= 0 && jj < HS) nsq += sq[ii * HS + jj];
        }
    ws[N_OFF + (size_t)n * L + t] = 1.f / fmaxf(sqrtf(nsq), 1e-4f);
}

// ---------------------------------------------------------------------------
// K1: Gram matrix G[l][p] = sum_c bs[c,l] * fs[c,p].  fp32, 128x128 tile,
// 8x8 micro-tile; staging now float4-coalesced from packed fs/bs.
__global__ __launch_bounds__(256) void k1_gram(float* __restrict__ ws) {
    int n = blockIdx.z;
    int l0 = blockIdx.y * 128, p0 = blockIdx.x * 128;
    int t = threadIdx.x;
    int tp = t >> 4, tm = t & 15;
    __shared__ float Bt[32][132];
    __shared__ float Ft[32][132];
    float acc[8][8] = {};
    const float* bsp = ws + BS_OFF + (size_t)n * NC * 1024;
    const float* fsp = ws + FS_OFF + (size_t)n * NC * 1024;
    for (int c0 = 0; c0 < NC; c0 += 32) {
        #pragma unroll
        for (int e = 0; e < 4; ++e) {
            int idx = t + e * 256;          // 0..1023 float4 slots
            int cl = idx >> 5, vq = idx & 31;
            *(float4*)&Bt[cl][vq * 4] =
                *(const float4*)&bsp[(size_t)(c0 + cl) * 1024 + l0 + vq * 4];
            *(float4*)&Ft[cl][vq * 4] =
                *(const float4*)&fsp[(size_t)(c0 + cl) * 1024 + p0 + vq * 4];
        }
        __syncthreads();
        for (int cl = 0; cl < 32; ++cl) {
            float4 a0 = *(const float4*)&Bt[cl][tp * 8];
            float4 a1 = *(const float4*)&Bt[cl][tp * 8 + 4];
            float4 b0 = *(const float4*)&Ft[cl][tm * 8];
            float4 b1 = *(const float4*)&Ft[cl][tm * 8 + 4];
            float av[8] = {a0.x, a0.y, a0.z, a0.w, a1.x, a1.y, a1.z, a1.w};
            float bv[8] = {b0.x, b0.y, b0.z, b0.w, b1.x, b1.y, b1.z, b1.w};
            #pragma unroll
            for (int aa = 0; aa < 8; ++aa)
                #pragma unroll
                for (int bb = 0; bb < 8; ++bb)
                    acc[aa][bb] += av[aa] * bv[bb];
        }
        __syncthreads();
    }
    float* G = ws + G_OFF + (size_t)n * L * L;
    #pragma unroll
    for (int aa = 0; aa < 8; ++aa) {
        int l = l0 + tp * 8 + aa;
        *(float4*)&G[(size_t)l * L + p0 + tm * 8] =
            make_float4(acc[aa][0], acc[aa][1], acc[aa][2], acc[aa][3]);
        *(float4*)&G[(size_t)l * L + p0 + tm * 8 + 4] =
            make_float4(acc[aa][4], acc[aa][5], acc[aa][6], acc[aa][7]);
    }
}

// ---------------------------------------------------------------------------
// K23 v2: fused score + first fuse + transpose, G staged in LDS.
// Stages G rows [i0-34, i0+66) x cols [j0-36, j0+68) (100x104 fp32, coalesced
// float4), computes the 34x34 A-halo from LDS (9 masked diagonal taps),
// then F1T[j][i] = sum_d A[i+d][j+d].  n pinned to XCD via bid&7 so the 4 MB
// G(n) lives in one XCD's L2.
__global__ __launch_bounds__(256) void k23_score_fuse1t(float* __restrict__ ws) {
    int bid = blockIdx.x;            // 8192
    int n = bid & 7;
    int tile = bid >> 3;             // 0..1023
    int i0 = (tile >> 5) * 32, j0 = (tile & 31) * 32;
    int t = threadIdx.x;
    __shared__ float Gs[100][104];
    __shared__ float sA[34][35];
    const float* G = ws + G_OFF + (size_t)n * L * L;
    const float* invn = ws + N_OFF + (size_t)n * L;
    for (int e = 0; e < 11; ++e) {
        int idx = t + e * 256;       // need 2600
        if (idx < 2600) {
            int row = idx / 26, q = idx - row * 26;
            int gr = i0 - 34 + row;
            int gc = j0 - 36 + q * 4;
            float4 v = make_float4(0.f, 0.f, 0.f, 0.f);
            if (gr >= 0 && gr < L && gc >= 0 && gc + 3 < L)
                v = *(const float4*)&G[(size_t)gr * L + gc];
            *(float4*)&Gs[row][q * 4] = v;
        }
    }
    __syncthreads();
    for (int e = 0; e < 5; ++e) {
        int idx = t + e * 256;
        if (idx < 1156) {
            int ih = idx / 34, jh = idx - ih * 34;
            int l = i0 - 1 + ih, p = j0 - 1 + jh;
            float a = 0.f;
            if (l >= 0 && l < L && p >= 0 && p < L) {
                int ly = l >> 5, lx = l & 31, py = p >> 5, px = p & 31;
                float s = 0.f;
                #pragma unroll
                for (int dy = -1; dy <= 1; ++dy) {
                    bool vy = (unsigned)(ly + dy) < HS && (unsigned)(py + dy) < HS;
                    #pragma unroll
                    for (int dx = -1; dx <= 1; ++dx) {
                        bool vx = (unsigned)(lx + dx) < HS && (unsigned)(px + dx) < HS;
                        int sh = dy * HS + dx;
                        float g = Gs[ih + 33 + sh][jh + 35 + sh];
                        s += (vy && vx) ? g : 0.f;
                    }
                }
                a = invn[l] * s;
            }
            sA[ih][jh] = a;
        }
    }
    __syncthreads();
    float* F1T = ws + F1T_OFF + (size_t)n * L * L;
    #pragma unroll
    for (int e = 0; e < 4; ++e) {
        int idx = t + e * 256;
        int jl = idx >> 5, il = idx & 31;
        float v = sA[il][jl] + sA[il + 1][jl + 1] + sA[il + 2][jl + 2];
        F1T[(size_t)(j0 + jl) * L + i0 + il] = v;
    }
}

// ---------------------------------------------------------------------------
// K4: second fuse (cm-flat diag 3-tap) + softmax over l; write bf16 Yb[p][k].
__global__ void k4_fuse2_softmax(float* __restrict__ ws) {
    int n = blockIdx.y, p = blockIdx.x, t = threadIdx.x;
    int py = p >> 5, px = p & 31;
    int Jc = px * HS + py;
    __shared__ float s3[3][32][33];
    __shared__ float red[8];
    const float* F1T = ws + F1T_OFF + (size_t)n * L * L;
    #pragma unroll
    for (int d = 0; d < 3; ++d) {
        int Jd = Jc + d - 1;
        bool ok = (Jd >= 0 && Jd < L);
        int rd = ok ? ((Jd & 31) * HS + (Jd >> 5)) : 0;
        const float* row = F1T + (size_t)rd * L;
        for (int e = 0; e < 4; ++e) {
            int i_ = t + e * 256;
            float v = ok ? row[i_] : 0.f;
            s3[d][i_ & 31][i_ >> 5] = v;
        }
    }
    __syncthreads();
    float vals[4];
    float mymax = -1e30f;
    #pragma unroll
    for (int e = 0; e < 4; ++e) {
        int kk = t + e * 256;
        float v = 0.f;
        #pragma unroll
        for (int d = 0; d < 3; ++d) {
            int kd = kk + d - 1;
            if (kd >= 0 && kd < L) v += s3[d][kd >> 5][kd & 31];
        }
        v *= 10.0f;
        vals[e] = v;
        mymax = fmaxf(mymax, v);
    }
    #pragma unroll
    for (int off = 32; off > 0; off >>= 1)
        mymax = fmaxf(mymax, __shfl_xor(mymax, off));
    if ((t & 63) == 0) red[t >> 6] = mymax;
    __syncthreads();
    float Mx = fmaxf(fmaxf(red[0], red[1]), fmaxf(red[2], red[3]));
    float mysum = 0.f;
    #pragma unroll
    for (int e = 0; e < 4; ++e) { vals[e] = __expf(vals[e] - Mx); mysum += vals[e]; }
    #pragma unroll
    for (int off = 32; off > 0; off >>= 1)
        mysum += __shfl_xor(mysum, off);
    if ((t & 63) == 0) red[4 + (t >> 6)] = mysum;
    __syncthreads();
    float rinv = 1.f / (red[4] + red[5] + red[6] + red[7]);
    unsigned short* Yb = (unsigned short*)((char*)ws + YB_B) + (size_t)n * L * L + (size_t)p * L;
    #pragma unroll
    for (int e = 0; e < 4; ++e) Yb[t + e * 256] = f2bf(vals[e] * rinv);
}

// ---------------------------------------------------------------------------
// K5: transposed bf16 deconv weights RWt[m][k], m = c*16+u*4+v, k cm l-order.
__global__ void k5_rwt(const float* __restrict__ b, float* __restrict__ ws) {
    int c = blockIdx.x, n = blockIdx.y;
    int t = threadIdx.x;
    __shared__ float pl[64][65];
    const float* bp = b + ((size_t)n * NC + c) * (HF * HF);
    for (int e = 0; e < 16; ++e) {
        int idx = t + e * 256;
        pl[idx >> 6][idx & 63] = bp[idx];
    }
    __syncthreads();
    unsigned short* RWt = (unsigned short*)((char*)ws + RWT_B) + ((size_t)n * MN + c * 16) * L;
    #pragma unroll
    for (int uv = 0; uv < 16; ++uv) {
        int u = uv >> 2, v = uv & 3;
        for (int e = 0; e < 4; ++e) {
            int k = t + e * 256;
            int ly = k & 31, lx = k >> 5;
            int r = 2 * ly - 1 + u, s = 2 * lx - 1 + v;
            float val = (r >= 0 && r < HF && s >= 0 && s < HF) ? pl[r][s] : 0.f;
            RWt[(size_t)uv * L + k] = f2bf(val);
        }
    }
}

// ---------------------------------------------------------------------------
// K6: Z[p][m] = sum_k Yb[p][k] * RWt[m][k] via bf16 MFMA 16x16x32.
// XCD-swizzled: each XCD owns one batch n.
__global__ __launch_bounds__(256) void k6_mfma_z(float* __restrict__ ws) {
    int bid = blockIdx.x + 12 * (blockIdx.y + 8 * blockIdx.z);   // 0..767
    int w = (bid & 7) * 96 + (bid >> 3);
    int mt = w % 12;
    int g = w / 12;                  // 0..63
    int n = g >> 3;
    int m0 = mt * 128;
    int p0 = (g & 7) * 128;
    int t = threadIdx.x;
    int lane = t & 63, wv = t >> 6;
    int wp = (wv >> 1) * 64, wm = (wv & 1) * 64;
    int fr = lane & 15, qd = lane >> 4;

    __shared__ unsigned short As[128][72];
    __shared__ unsigned short Bs[128][72];

    const unsigned short* Ybp = (const unsigned short*)((const char*)ws + YB_B) + (size_t)n * L * L;
    const unsigned short* RWtp = (const unsigned short*)((const char*)ws + RWT_B) + (size_t)n * MN * L;

    float4v acc[4][4] = {};

    for (int k0 = 0; k0 < L; k0 += 64) {
        __syncthreads();
        #pragma unroll
        for (int e = 0; e < 4; ++e) {
            int id = t + e * 256;
            int row = id >> 3, cb = id & 7;
            *(short8*)&As[row][cb * 8] =
                *(const short8*)(Ybp + (size_t)(p0 + row) * L + k0 + cb * 8);
            *(short8*)&Bs[row][cb * 8] =
                *(const short8*)(RWtp + (size_t)(m0 + row) * L + k0 + cb * 8);
        }
        __syncthreads();
        #pragma unroll
        for (int ks = 0; ks < 2; ++ks) {
            short8 af[4], bf[4];
            #pragma unroll
            for (int a = 0; a < 4; ++a)
                af[a] = *(const short8*)&As[wp + a * 16 + fr][ks * 32 + qd * 8];
            #pragma unroll
            for (int bq = 0; bq < 4; ++bq)
                bf[bq] = *(const short8*)&Bs[wm + bq * 16 + fr][ks * 32 + qd * 8];
            #pragma unroll
            for (int a = 0; a < 4; ++a)
                #pragma unroll
                for (int bq = 0; bq < 4; ++bq)
                    acc[a][bq] = __builtin_amdgcn_mfma_f32_16x16x32_bf16(
                        af[a], bf[bq], acc[a][bq], 0, 0, 0);
        }
    }

    float* Zp = ws + Z_OFF + (size_t)n * L * MN;
    #pragma unroll
    for (int a = 0; a < 4; ++a) {
        #pragma unroll
        for (int r = 0; r < 4; ++r) {
            int p = p0 + wp + a * 16 + qd * 4 + r;
            #pragma unroll
            for (int bq = 0; bq < 4; ++bq) {
                int m = m0 + wm + bq * 16 + fr;
                Zp[(size_t)p * MN + m] = acc[a][bq][r];
            }
        }
    }
}

// ---------------------------------------------------------------------------
// K7: deterministic gather epilogue — each output pixel reads its <=4 Z
// entries (staged via LDS) and does one plain store.
__global__ __launch_bounds__(256) void k7_gather(const float* __restrict__ ws,
                                                 float* __restrict__ out) {
    int yq = blockIdx.x, c = blockIdx.y, n = blockIdx.z;
    int t = threadIdx.x;
    int y0 = yq * 4;
    int ibase = (y0 >> 1) - 1;
    __shared__ float zs[128][17];
    const float* Zp = ws + Z_OFF + (size_t)n * L * MN;
    #pragma unroll
    for (int e = 0; e < 2; ++e) {
        int idx = t + e * 256;
        int pl = idx >> 2, q = idx & 3;
        int il = pl >> 5, j = pl & 31;
        int i = ibase + il;
        float4 v = make_float4(0.f, 0.f, 0.f, 0.f);
        if (i >= 0 && i < HS)
            v = *(const float4*)&Zp[(size_t)(i * HS + j) * MN + c * 16 + q * 4];
        zs[pl][q * 4 + 0] = v.x;
        zs[pl][q * 4 + 1] = v.y;
        zs[pl][q * 4 + 2] = v.z;
        zs[pl][q * 4 + 3] = v.w;
    }
    __syncthreads();
    int y = y0 + (t >> 6), x = t & 63;
    int ih = (y + 1) >> 1, jh = (x + 1) >> 1;
    float s = 0.f;
    #pragma unroll
    for (int di = 0; di < 2; ++di) {
        int i = ih - di;
        if (i < 0 || i >= HS) continue;
        int u = y + 1 - 2 * i;
        int il = i - ibase;
        #pragma unroll
        for (int dj = 0; dj < 2; ++dj) {
            int j = jh - dj;
            if (j < 0 || j >= HS) continue;
            int v = x + 1 - 2 * j;
            s += zs[il * 32 + j][u * 4 + v];
        }
    }
    out[(((size_t)n * NC + c) * HF + y) * HF + x] = 0.25f * s;
}

// ---------------------------------------------------------------------------
extern "C" void kernel_launch(void* const* d_in, const int* in_sizes, int n_in,
                              void* d_out, int out_size, void* d_ws, size_t ws_size,
                              hipStream_t stream) {
    const float* f = (const float*)d_in[0];
    const float* b = (const float*)d_in[1];
    float* out = (float*)d_out;
    float* ws = (float*)d_ws;

    kpre_pack<<<dim3(NC, 2, NB), 256, 0, stream>>>(f, b, ws);
    k0_norm<<<NB, 1024, 0, stream>>>(ws);
    k1_gram<<<dim3(8, 8, NB), 256, 0, stream>>>(ws);
    k23_score_fuse1t<<<8192, 256, 0, stream>>>(ws);
    k4_fuse2_softmax<<<dim3(1024, NB), 256, 0, stream>>>(ws);
    k5_rwt<<<dim3(NC, NB), 256, 0, stream>>>(b, ws);
    k6_mfma_z<<<dim3(12, 8, NB), 256, 0, stream>>>(ws);
    k7_gather<<<dim3(16, NC, NB), 256, 0, stream>>>(ws, out);
}

// Round 6
// 217.889 us; speedup vs baseline: 4.7437x; 1.1410x over previous
//
#include <hip/hip_runtime.h>
#include <math.h>

#define NB 8
#define NC 96
#define HF 64
#define HS 32
#define L 1024
#define MN 1536   // 96 * 16 taps

// workspace layout — all regions disjoint & type-pure during their lifetime:
//  G   (float) : [NB][L][L]   gram                       bytes [0, 32M)
//  F1T (float) : [NB][L][L]   fused+transposed scores    bytes [32M, 64M)
//  YB  (bf16)  : [NB][L][L]   softmax probs [p][k]       bytes [64M, 80M)
//  RWT (bf16)  : [NB][MN][L]  deconv weights [m][k]      bytes [80M, 104M)
//  N   (float) : [NB][L]      inv patch norms            @104M
//  FS  (float) : [NB][NC][1024] packed f[::2,::2]        @104M+32K
//  BS  (float) : [NB][NC][1024] packed b[::2,::2]        after FS
//  Z   (float) : [NB][L][MN]  deconv matmul result       bytes [0, 50.3M)
//                (overlays G+F1T, both dead before k6)
#define G_OFF    0ull
#define F1T_OFF  (8ull * 1024 * 1024)           // float offset
#define YB_B     (64ull * 1024 * 1024)          // byte offset
#define RWT_B    (80ull * 1024 * 1024)          // byte offset
#define N_OFF    (27262976ull)                  // float offset (104 MB)
#define FS_OFF   (27271168ull)                  // float offset
#define BS_OFF   (28057600ull)                  // float offset
#define Z_OFF    0ull                           // float offset

typedef __attribute__((ext_vector_type(8))) short short8;
typedef __attribute__((ext_vector_type(4))) float float4v;

__device__ inline unsigned short f2bf(float x) {
    union { float f; unsigned u; } v; v.f = x;
    unsigned r = v.u + 0x7fff + ((v.u >> 16) & 1);   // RNE
    return (unsigned short)(r >> 16);
}

// ---------------------------------------------------------------------------
// KPRE: extract ::2,::2 planes of f and b into packed buffers.  XCD-pinned:
// bid%8 == n so FS/BS(n) land in XCD n's L2 for k0/k1.
__global__ void kpre_pack(const float* __restrict__ f, const float* __restrict__ b,
                          float* __restrict__ ws) {
    int n = blockIdx.x, c = blockIdx.y, which = blockIdx.z;
    const float* src = (which ? b : f) + ((size_t)n * NC + c) * (HF * HF);
    float* dst = ws + (which ? BS_OFF : FS_OFF) + ((size_t)n * NC + c) * 1024;
    int t = threadIdx.x;
    #pragma unroll
    for (int e = 0; e < 4; ++e) {
        int pos = t + e * 256;
        int i = pos >> 5, j = pos & 31;
        dst[pos] = src[(2 * i) * HF + 2 * j];
    }
}

// ---------------------------------------------------------------------------
// K0: inv patch norms from packed bs.  bid == n -> XCD-pinned.
__global__ void k0_norm(float* __restrict__ ws) {
    int n = blockIdx.x;
    int t = threadIdx.x;
    int i = t >> 5, j = t & 31;
    __shared__ float sq[1024];
    const float* bsp = ws + BS_OFF + (size_t)n * NC * 1024;
    float s = 0.f;
    for (int c = 0; c < NC; ++c) {
        float v = bsp[(size_t)c * 1024 + t];
        s += v * v;
    }
    sq[t] = s;
    __syncthreads();
    float nsq = 0.f;
    #pragma unroll
    for (int dy = -1; dy <= 1; ++dy)
        #pragma unroll
        for (int dx = -1; dx <= 1; ++dx) {
            int ii = i + dy, jj = j + dx;
            if (ii >= 0 && ii < HS && jj >= 0 && jj < HS) nsq += sq[ii * HS + jj];
        }
    ws[N_OFF + (size_t)n * L + t] = 1.f / fmaxf(sqrtf(nsq), 1e-4f);
}

// ---------------------------------------------------------------------------
// K1: Gram G[l][p] = sum_c bs[c,l]*fs[c,p].  fp32 128x128 tile, 8x8 micro.
// Grid (8,8,8): x = n (XCD pin), y = p-tile, z = l-tile.
__global__ __launch_bounds__(256) void k1_gram(float* __restrict__ ws) {
    int n = blockIdx.x;
    int p0 = blockIdx.y * 128, l0 = blockIdx.z * 128;
    int t = threadIdx.x;
    int tp = t >> 4, tm = t & 15;
    __shared__ float Bt[32][132];
    __shared__ float Ft[32][132];
    float acc[8][8] = {};
    const float* bsp = ws + BS_OFF + (size_t)n * NC * 1024;
    const float* fsp = ws + FS_OFF + (size_t)n * NC * 1024;
    for (int c0 = 0; c0 < NC; c0 += 32) {
        #pragma unroll
        for (int e = 0; e < 4; ++e) {
            int idx = t + e * 256;
            int cl = idx >> 5, vq = idx & 31;
            *(float4*)&Bt[cl][vq * 4] =
                *(const float4*)&bsp[(size_t)(c0 + cl) * 1024 + l0 + vq * 4];
            *(float4*)&Ft[cl][vq * 4] =
                *(const float4*)&fsp[(size_t)(c0 + cl) * 1024 + p0 + vq * 4];
        }
        __syncthreads();
        for (int cl = 0; cl < 32; ++cl) {
            float4 a0 = *(const float4*)&Bt[cl][tp * 8];
            float4 a1 = *(const float4*)&Bt[cl][tp * 8 + 4];
            float4 b0 = *(const float4*)&Ft[cl][tm * 8];
            float4 b1 = *(const float4*)&Ft[cl][tm * 8 + 4];
            float av[8] = {a0.x, a0.y, a0.z, a0.w, a1.x, a1.y, a1.z, a1.w};
            float bv[8] = {b0.x, b0.y, b0.z, b0.w, b1.x, b1.y, b1.z, b1.w};
            #pragma unroll
            for (int aa = 0; aa < 8; ++aa)
                #pragma unroll
                for (int bb = 0; bb < 8; ++bb)
                    acc[aa][bb] += av[aa] * bv[bb];
        }
        __syncthreads();
    }
    float* G = ws + G_OFF + (size_t)n * L * L;
    #pragma unroll
    for (int aa = 0; aa < 8; ++aa) {
        int l = l0 + tp * 8 + aa;
        *(float4*)&G[(size_t)l * L + p0 + tm * 8] =
            make_float4(acc[aa][0], acc[aa][1], acc[aa][2], acc[aa][3]);
        *(float4*)&G[(size_t)l * L + p0 + tm * 8 + 4] =
            make_float4(acc[aa][4], acc[aa][5], acc[aa][6], acc[aa][7]);
    }
}

// ---------------------------------------------------------------------------
// K23 v3: fused score + first fuse + transpose, SEPARABLE taps.
// U[l][p] = sum_dy G[l+32dy][p+32dy]  (3 coalesced global taps, flat-bound
//   masked — equivalent to the y-masks for all consumed cells),
// A[l][p] = invn[l] * sum_dx maskx U[l+dx][p+dx]  (3 LDS taps),
// F1T[j][i] = sum_d A[i+d][j+d].
// LDS ~10.5 KB (was 46.6) -> ~8 blocks/CU.  n = bid&7 XCD pin (G(n) in L2).
__global__ __launch_bounds__(256) void k23_score_fuse1t(float* __restrict__ ws) {
    int bid = blockIdx.x;            // 8192
    int n = bid & 7;
    int tile = bid >> 3;             // 0..1023
    int i0 = (tile >> 5) * 32, j0 = (tile & 31) * 32;
    int t = threadIdx.x;
    __shared__ float U[36][37];
    __shared__ float sA[34][35];
    __shared__ float sinv[34];
    const float* G = ws + G_OFF + (size_t)n * L * L;
    const float* invn = ws + N_OFF + (size_t)n * L;
    if (t < 34) {
        int l = i0 - 1 + t;
        sinv[t] = ((unsigned)l < L) ? invn[l] : 0.f;
    }
    for (int e = 0; e < 6; ++e) {
        int idx = t + e * 256;       // need 1296
        if (idx < 1296) {
            int a = idx / 36, bq = idx - a * 36;
            int l = i0 - 2 + a, p = j0 - 2 + bq;
            float s = 0.f;
            #pragma unroll
            for (int dy = -1; dy <= 1; ++dy) {
                int ll = l + dy * 32, pp = p + dy * 32;
                if ((unsigned)ll < L && (unsigned)pp < L)
                    s += G[(size_t)ll * L + pp];
            }
            U[a][bq] = s;
        }
    }
    __syncthreads();
    for (int e = 0; e < 5; ++e) {
        int idx = t + e * 256;
        if (idx < 1156) {
            int ih = idx / 34, jh = idx - ih * 34;
            int l = i0 - 1 + ih, p = j0 - 1 + jh;
            float a = 0.f;
            if ((unsigned)l < L && (unsigned)p < L) {
                int lx = l & 31, px = p & 31;
                float s = 0.f;
                #pragma unroll
                for (int dx = -1; dx <= 1; ++dx) {
                    bool ok = (unsigned)(lx + dx) < HS && (unsigned)(px + dx) < HS;
                    float u = U[ih + 1 + dx][jh + 1 + dx];
                    s += ok ? u : 0.f;
                }
                a = sinv[ih] * s;
            }
            sA[ih][jh] = a;
        }
    }
    __syncthreads();
    float* F1T = ws + F1T_OFF + (size_t)n * L * L;
    #pragma unroll
    for (int e = 0; e < 4; ++e) {
        int idx = t + e * 256;
        int jl = idx >> 5, il = idx & 31;
        float v = sA[il][jl] + sA[il + 1][jl + 1] + sA[il + 2][jl + 2];
        F1T[(size_t)(j0 + jl) * L + i0 + il] = v;
    }
}

// ---------------------------------------------------------------------------
// K4: second fuse (cm-flat diag 3-tap) + softmax; bf16 Yb[p][k].
// 1D grid 8192, n = bid&7 (XCD pin: F1T(n) = 4 MB resident in XCD L2).
__global__ void k4_fuse2_softmax(float* __restrict__ ws) {
    int bid = blockIdx.x;
    int n = bid & 7, p = bid >> 3;
    int t = threadIdx.x;
    int py = p >> 5, px = p & 31;
    int Jc = px * HS + py;
    __shared__ float s3[3][32][33];
    __shared__ float red[8];
    const float* F1T = ws + F1T_OFF + (size_t)n * L * L;
    #pragma unroll
    for (int d = 0; d < 3; ++d) {
        int Jd = Jc + d - 1;
        bool ok = (Jd >= 0 && Jd < L);
        int rd = ok ? ((Jd & 31) * HS + (Jd >> 5)) : 0;
        const float* row = F1T + (size_t)rd * L;
        for (int e = 0; e < 4; ++e) {
            int i_ = t + e * 256;
            float v = ok ? row[i_] : 0.f;
            s3[d][i_ & 31][i_ >> 5] = v;
        }
    }
    __syncthreads();
    float vals[4];
    float mymax = -1e30f;
    #pragma unroll
    for (int e = 0; e < 4; ++e) {
        int kk = t + e * 256;
        float v = 0.f;
        #pragma unroll
        for (int d = 0; d < 3; ++d) {
            int kd = kk + d - 1;
            if (kd >= 0 && kd < L) v += s3[d][kd >> 5][kd & 31];
        }
        v *= 10.0f;
        vals[e] = v;
        mymax = fmaxf(mymax, v);
    }
    #pragma unroll
    for (int off = 32; off > 0; off >>= 1)
        mymax = fmaxf(mymax, __shfl_xor(mymax, off));
    if ((t & 63) == 0) red[t >> 6] = mymax;
    __syncthreads();
    float Mx = fmaxf(fmaxf(red[0], red[1]), fmaxf(red[2], red[3]));
    float mysum = 0.f;
    #pragma unroll
    for (int e = 0; e < 4; ++e) { vals[e] = __expf(vals[e] - Mx); mysum += vals[e]; }
    #pragma unroll
    for (int off = 32; off > 0; off >>= 1)
        mysum += __shfl_xor(mysum, off);
    if ((t & 63) == 0) red[4 + (t >> 6)] = mysum;
    __syncthreads();
    float rinv = 1.f / (red[4] + red[5] + red[6] + red[7]);
    unsigned short* Yb = (unsigned short*)((char*)ws + YB_B) + (size_t)n * L * L + (size_t)p * L;
    #pragma unroll
    for (int e = 0; e < 4; ++e) Yb[t + e * 256] = f2bf(vals[e] * rinv);
}

// ---------------------------------------------------------------------------
// K5: transposed bf16 deconv weights RWt[m][k].  Grid (8,96): x = n (pin).
__global__ void k5_rwt(const float* __restrict__ b, float* __restrict__ ws) {
    int n = blockIdx.x, c = blockIdx.y;
    int t = threadIdx.x;
    __shared__ float pl[64][65];
    const float* bp = b + ((size_t)n * NC + c) * (HF * HF);
    for (int e = 0; e < 16; ++e) {
        int idx = t + e * 256;
        pl[idx >> 6][idx & 63] = bp[idx];
    }
    __syncthreads();
    unsigned short* RWt = (unsigned short*)((char*)ws + RWT_B) + ((size_t)n * MN + c * 16) * L;
    #pragma unroll
    for (int uv = 0; uv < 16; ++uv) {
        int u = uv >> 2, v = uv & 3;
        for (int e = 0; e < 4; ++e) {
            int k = t + e * 256;
            int ly = k & 31, lx = k >> 5;
            int r = 2 * ly - 1 + u, s = 2 * lx - 1 + v;
            float val = (r >= 0 && r < HF && s >= 0 && s < HF) ? pl[r][s] : 0.f;
            RWt[(size_t)uv * L + k] = f2bf(val);
        }
    }
}

// ---------------------------------------------------------------------------
// K6: Z[p][m] = sum_k Yb[p][k] * RWt[m][k] via bf16 MFMA 16x16x32.
// Grid (8,12,8): x = n (XCD pin — Yb(n)+RWt(n) ~5 MB near-resident).
__global__ __launch_bounds__(256) void k6_mfma_z(float* __restrict__ ws) {
    int n = blockIdx.x;
    int m0 = blockIdx.y * 128;
    int p0 = blockIdx.z * 128;
    int t = threadIdx.x;
    int lane = t & 63, wv = t >> 6;
    int wp = (wv >> 1) * 64, wm = (wv & 1) * 64;
    int fr = lane & 15, qd = lane >> 4;

    __shared__ unsigned short As[128][72];
    __shared__ unsigned short Bs[128][72];

    const unsigned short* Ybp = (const unsigned short*)((const char*)ws + YB_B) + (size_t)n * L * L;
    const unsigned short* RWtp = (const unsigned short*)((const char*)ws + RWT_B) + (size_t)n * MN * L;

    float4v acc[4][4] = {};

    for (int k0 = 0; k0 < L; k0 += 64) {
        __syncthreads();
        #pragma unroll
        for (int e = 0; e < 4; ++e) {
            int id = t + e * 256;
            int row = id >> 3, cb = id & 7;
            *(short8*)&As[row][cb * 8] =
                *(const short8*)(Ybp + (size_t)(p0 + row) * L + k0 + cb * 8);
            *(short8*)&Bs[row][cb * 8] =
                *(const short8*)(RWtp + (size_t)(m0 + row) * L + k0 + cb * 8);
        }
        __syncthreads();
        #pragma unroll
        for (int ks = 0; ks < 2; ++ks) {
            short8 af[4], bf[4];
            #pragma unroll
            for (int a = 0; a < 4; ++a)
                af[a] = *(const short8*)&As[wp + a * 16 + fr][ks * 32 + qd * 8];
            #pragma unroll
            for (int bq = 0; bq < 4; ++bq)
                bf[bq] = *(const short8*)&Bs[wm + bq * 16 + fr][ks * 32 + qd * 8];
            #pragma unroll
            for (int a = 0; a < 4; ++a)
                #pragma unroll
                for (int bq = 0; bq < 4; ++bq)
                    acc[a][bq] = __builtin_amdgcn_mfma_f32_16x16x32_bf16(
                        af[a], bf[bq], acc[a][bq], 0, 0, 0);
        }
    }

    float* Zp = ws + Z_OFF + (size_t)n * L * MN;
    #pragma unroll
    for (int a = 0; a < 4; ++a) {
        #pragma unroll
        for (int r = 0; r < 4; ++r) {
            int p = p0 + wp + a * 16 + qd * 4 + r;
            #pragma unroll
            for (int bq = 0; bq < 4; ++bq) {
                int m = m0 + wm + bq * 16 + fr;
                Zp[(size_t)p * MN + m] = acc[a][bq][r];
            }
        }
    }
}

// ---------------------------------------------------------------------------
// K7: gather epilogue.  Grid (8,16,96): x = n (XCD pin — Z(n) from k6's L2).
__global__ __launch_bounds__(256) void k7_gather(const float* __restrict__ ws,
                                                 float* __restrict__ out) {
    int n = blockIdx.x, yq = blockIdx.y, c = blockIdx.z;
    int t = threadIdx.x;
    int y0 = yq * 4;
    int ibase = (y0 >> 1) - 1;
    __shared__ float zs[128][17];
    const float* Zp = ws + Z_OFF + (size_t)n * L * MN;
    #pragma unroll
    for (int e = 0; e < 2; ++e) {
        int idx = t + e * 256;
        int pl = idx >> 2, q = idx & 3;
        int il = pl >> 5, j = pl & 31;
        int i = ibase + il;
        float4 v = make_float4(0.f, 0.f, 0.f, 0.f);
        if (i >= 0 && i < HS)
            v = *(const float4*)&Zp[(size_t)(i * HS + j) * MN + c * 16 + q * 4];
        zs[pl][q * 4 + 0] = v.x;
        zs[pl][q * 4 + 1] = v.y;
        zs[pl][q * 4 + 2] = v.z;
        zs[pl][q * 4 + 3] = v.w;
    }
    __syncthreads();
    int y = y0 + (t >> 6), x = t & 63;
    int ih = (y + 1) >> 1, jh = (x + 1) >> 1;
    float s = 0.f;
    #pragma unroll
    for (int di = 0; di < 2; ++di) {
        int i = ih - di;
        if (i < 0 || i >= HS) continue;
        int u = y + 1 - 2 * i;
        int il = i - ibase;
        #pragma unroll
        for (int dj = 0; dj < 2; ++dj) {
            int j = jh - dj;
            if (j < 0 || j >= HS) continue;
            int v = x + 1 - 2 * j;
            s += zs[il * 32 + j][u * 4 + v];
        }
    }
    out[(((size_t)n * NC + c) * HF + y) * HF + x] = 0.25f * s;
}

// ---------------------------------------------------------------------------
extern "C" void kernel_launch(void* const* d_in, const int* in_sizes, int n_in,
                              void* d_out, int out_size, void* d_ws, size_t ws_size,
                              hipStream_t stream) {
    const float* f = (const float*)d_in[0];
    const float* b = (const float*)d_in[1];
    float* out = (float*)d_out;
    float* ws = (float*)d_ws;

    kpre_pack<<<dim3(NB, NC, 2), 256, 0, stream>>>(f, b, ws);
    k0_norm<<<NB, 1024, 0, stream>>>(ws);
    k1_gram<<<dim3(NB, 8, 8), 256, 0, stream>>>(ws);
    k23_score_fuse1t<<<8192, 256, 0, stream>>>(ws);
    k4_fuse2_softmax<<<8192, 256, 0, stream>>>(ws);
    k5_rwt<<<dim3(NB, NC), 256, 0, stream>>>(b, ws);
    k6_mfma_z<<<dim3(NB, 12, 8), 256, 0, stream>>>(ws);
    k7_gather<<<dim3(NB, 16, NC), 256, 0, stream>>>(ws, out);
}

// Round 7
// 209.626 us; speedup vs baseline: 4.9306x; 1.0394x over previous
//
#include <hip/hip_runtime.h>
#include <math.h>

#define NB 8
#define NC 96
#define HF 64
#define HS 32
#define L 1024
#define MN 1536   // 96 * 16 taps

// workspace layout — all regions disjoint & type-pure during their lifetime:
//  G   (float) : [NB][L][L]   gram                       bytes [0, 32M)
//  F1T (float) : [NB][L][L]   fused+transposed scores    bytes [32M, 64M)
//  YBF (bf16)  : [NB][64][32][64][8]  softmax probs in MFMA-A-fragment order
//                (pt, kc, lane, j)                       bytes [64M, 80M)
//  RWTF(bf16)  : [NB][96][32][64][8]  deconv weights in MFMA-B-fragment order
//                (mt, kc, lane, j)                       bytes [80M, 104M)
//  N   (float) : [NB][L]      inv patch norms            @104M
//  FS  (float) : [NB][NC][1024] packed f[::2,::2]        @104M+32K
//  BS  (float) : [NB][NC][1024] packed b[::2,::2]        after FS
//  Z   (float) : [NB][L][MN]  deconv matmul result       bytes [0, 50.3M)
//                (overlays G+F1T, both dead before k6)
#define G_OFF    0ull
#define F1T_OFF  (8ull * 1024 * 1024)           // float offset
#define YB_B     (64ull * 1024 * 1024)          // byte offset
#define RWT_B    (80ull * 1024 * 1024)          // byte offset
#define N_OFF    (27262976ull)                  // float offset (104 MB)
#define FS_OFF   (27271168ull)                  // float offset
#define BS_OFF   (28057600ull)                  // float offset
#define Z_OFF    0ull                           // float offset

typedef __attribute__((ext_vector_type(8))) short short8;
typedef __attribute__((ext_vector_type(4))) float float4v;

__device__ inline unsigned short f2bf(float x) {
    union { float f; unsigned u; } v; v.f = x;
    unsigned r = v.u + 0x7fff + ((v.u >> 16) & 1);   // RNE
    return (unsigned short)(r >> 16);
}

// ---------------------------------------------------------------------------
// KPRE: extract ::2,::2 planes of f and b into packed buffers.  XCD-pinned.
__global__ void kpre_pack(const float* __restrict__ f, const float* __restrict__ b,
                          float* __restrict__ ws) {
    int n = blockIdx.x, c = blockIdx.y, which = blockIdx.z;
    const float* src = (which ? b : f) + ((size_t)n * NC + c) * (HF * HF);
    float* dst = ws + (which ? BS_OFF : FS_OFF) + ((size_t)n * NC + c) * 1024;
    int t = threadIdx.x;
    #pragma unroll
    for (int e = 0; e < 4; ++e) {
        int pos = t + e * 256;
        int i = pos >> 5, j = pos & 31;
        dst[pos] = src[(2 * i) * HF + 2 * j];
    }
}

// ---------------------------------------------------------------------------
// K0: inv patch norms from packed bs.  bid == n -> XCD-pinned.
__global__ void k0_norm(float* __restrict__ ws) {
    int n = blockIdx.x;
    int t = threadIdx.x;
    int i = t >> 5, j = t & 31;
    __shared__ float sq[1024];
    const float* bsp = ws + BS_OFF + (size_t)n * NC * 1024;
    float s = 0.f;
    for (int c = 0; c < NC; ++c) {
        float v = bsp[(size_t)c * 1024 + t];
        s += v * v;
    }
    sq[t] = s;
    __syncthreads();
    float nsq = 0.f;
    #pragma unroll
    for (int dy = -1; dy <= 1; ++dy)
        #pragma unroll
        for (int dx = -1; dx <= 1; ++dx) {
            int ii = i + dy, jj = j + dx;
            if (ii >= 0 && ii < HS && jj >= 0 && jj < HS) nsq += sq[ii * HS + jj];
        }
    ws[N_OFF + (size_t)n * L + t] = 1.f / fmaxf(sqrtf(nsq), 1e-4f);
}

// ---------------------------------------------------------------------------
// K1: Gram G[l][p] = sum_c bs[c,l]*fs[c,p].  fp32 128x128 tile, 8x8 micro.
__global__ __launch_bounds__(256) void k1_gram(float* __restrict__ ws) {
    int n = blockIdx.x;
    int p0 = blockIdx.y * 128, l0 = blockIdx.z * 128;
    int t = threadIdx.x;
    int tp = t >> 4, tm = t & 15;
    __shared__ float Bt[32][132];
    __shared__ float Ft[32][132];
    float acc[8][8] = {};
    const float* bsp = ws + BS_OFF + (size_t)n * NC * 1024;
    const float* fsp = ws + FS_OFF + (size_t)n * NC * 1024;
    for (int c0 = 0; c0 < NC; c0 += 32) {
        #pragma unroll
        for (int e = 0; e < 4; ++e) {
            int idx = t + e * 256;
            int cl = idx >> 5, vq = idx & 31;
            *(float4*)&Bt[cl][vq * 4] =
                *(const float4*)&bsp[(size_t)(c0 + cl) * 1024 + l0 + vq * 4];
            *(float4*)&Ft[cl][vq * 4] =
                *(const float4*)&fsp[(size_t)(c0 + cl) * 1024 + p0 + vq * 4];
        }
        __syncthreads();
        for (int cl = 0; cl < 32; ++cl) {
            float4 a0 = *(const float4*)&Bt[cl][tp * 8];
            float4 a1 = *(const float4*)&Bt[cl][tp * 8 + 4];
            float4 b0 = *(const float4*)&Ft[cl][tm * 8];
            float4 b1 = *(const float4*)&Ft[cl][tm * 8 + 4];
            float av[8] = {a0.x, a0.y, a0.z, a0.w, a1.x, a1.y, a1.z, a1.w};
            float bv[8] = {b0.x, b0.y, b0.z, b0.w, b1.x, b1.y, b1.z, b1.w};
            #pragma unroll
            for (int aa = 0; aa < 8; ++aa)
                #pragma unroll
                for (int bb = 0; bb < 8; ++bb)
                    acc[aa][bb] += av[aa] * bv[bb];
        }
        __syncthreads();
    }
    float* G = ws + G_OFF + (size_t)n * L * L;
    #pragma unroll
    for (int aa = 0; aa < 8; ++aa) {
        int l = l0 + tp * 8 + aa;
        *(float4*)&G[(size_t)l * L + p0 + tm * 8] =
            make_float4(acc[aa][0], acc[aa][1], acc[aa][2], acc[aa][3]);
        *(float4*)&G[(size_t)l * L + p0 + tm * 8 + 4] =
            make_float4(acc[aa][4], acc[aa][5], acc[aa][6], acc[aa][7]);
    }
}

// ---------------------------------------------------------------------------
// K23: fused score + first fuse + transpose, separable taps (see r6).
__global__ __launch_bounds__(256) void k23_score_fuse1t(float* __restrict__ ws) {
    int bid = blockIdx.x;            // 8192
    int n = bid & 7;
    int tile = bid >> 3;             // 0..1023
    int i0 = (tile >> 5) * 32, j0 = (tile & 31) * 32;
    int t = threadIdx.x;
    __shared__ float U[36][37];
    __shared__ float sA[34][35];
    __shared__ float sinv[34];
    const float* G = ws + G_OFF + (size_t)n * L * L;
    const float* invn = ws + N_OFF + (size_t)n * L;
    if (t < 34) {
        int l = i0 - 1 + t;
        sinv[t] = ((unsigned)l < L) ? invn[l] : 0.f;
    }
    for (int e = 0; e < 6; ++e) {
        int idx = t + e * 256;       // need 1296
        if (idx < 1296) {
            int a = idx / 36, bq = idx - a * 36;
            int l = i0 - 2 + a, p = j0 - 2 + bq;
            float s = 0.f;
            #pragma unroll
            for (int dy = -1; dy <= 1; ++dy) {
                int ll = l + dy * 32, pp = p + dy * 32;
                if ((unsigned)ll < L && (unsigned)pp < L)
                    s += G[(size_t)ll * L + pp];
            }
            U[a][bq] = s;
        }
    }
    __syncthreads();
    for (int e = 0; e < 5; ++e) {
        int idx = t + e * 256;
        if (idx < 1156) {
            int ih = idx / 34, jh = idx - ih * 34;
            int l = i0 - 1 + ih, p = j0 - 1 + jh;
            float a = 0.f;
            if ((unsigned)l < L && (unsigned)p < L) {
                int lx = l & 31, px = p & 31;
                float s = 0.f;
                #pragma unroll
                for (int dx = -1; dx <= 1; ++dx) {
                    bool ok = (unsigned)(lx + dx) < HS && (unsigned)(px + dx) < HS;
                    float u = U[ih + 1 + dx][jh + 1 + dx];
                    s += ok ? u : 0.f;
                }
                a = sinv[ih] * s;
            }
            sA[ih][jh] = a;
        }
    }
    __syncthreads();
    float* F1T = ws + F1T_OFF + (size_t)n * L * L;
    #pragma unroll
    for (int e = 0; e < 4; ++e) {
        int idx = t + e * 256;
        int jl = idx >> 5, il = idx & 31;
        float v = sA[il][jl] + sA[il + 1][jl + 1] + sA[il + 2][jl + 2];
        F1T[(size_t)(j0 + jl) * L + i0 + il] = v;
    }
}

// ---------------------------------------------------------------------------
// K4: second fuse (cm-flat diag 3-tap) + softmax; write bf16 Yb in MFMA
// A-fragment order: YbF[pt][kc][lane=qd*16+fr][j] = Yb[pt*16+fr][kc*32+qd*8+j].
__global__ void k4_fuse2_softmax(float* __restrict__ ws) {
    int bid = blockIdx.x;
    int n = bid & 7, p = bid >> 3;
    int t = threadIdx.x;
    int py = p >> 5, px = p & 31;
    int Jc = px * HS + py;
    __shared__ float s3[3][32][33];
    __shared__ float red[8];
    const float* F1T = ws + F1T_OFF + (size_t)n * L * L;
    #pragma unroll
    for (int d = 0; d < 3; ++d) {
        int Jd = Jc + d - 1;
        bool ok = (Jd >= 0 && Jd < L);
        int rd = ok ? ((Jd & 31) * HS + (Jd >> 5)) : 0;
        const float* row = F1T + (size_t)rd * L;
        for (int e = 0; e < 4; ++e) {
            int i_ = t + e * 256;
            float v = ok ? row[i_] : 0.f;
            s3[d][i_ & 31][i_ >> 5] = v;
        }
    }
    __syncthreads();
    float vals[4];
    float mymax = -1e30f;
    #pragma unroll
    for (int e = 0; e < 4; ++e) {
        int kk = t + e * 256;
        float v = 0.f;
        #pragma unroll
        for (int d = 0; d < 3; ++d) {
            int kd = kk + d - 1;
            if (kd >= 0 && kd < L) v += s3[d][kd >> 5][kd & 31];
        }
        v *= 10.0f;
        vals[e] = v;
        mymax = fmaxf(mymax, v);
    }
    #pragma unroll
    for (int off = 32; off > 0; off >>= 1)
        mymax = fmaxf(mymax, __shfl_xor(mymax, off));
    if ((t & 63) == 0) red[t >> 6] = mymax;
    __syncthreads();
    float Mx = fmaxf(fmaxf(red[0], red[1]), fmaxf(red[2], red[3]));
    float mysum = 0.f;
    #pragma unroll
    for (int e = 0; e < 4; ++e) { vals[e] = __expf(vals[e] - Mx); mysum += vals[e]; }
    #pragma unroll
    for (int off = 32; off > 0; off >>= 1)
        mysum += __shfl_xor(mysum, off);
    if ((t & 63) == 0) red[4 + (t >> 6)] = mysum;
    __syncthreads();
    float rinv = 1.f / (red[4] + red[5] + red[6] + red[7]);
    unsigned short* YbF = (unsigned short*)((char*)ws + YB_B) + (size_t)n * L * L;
    int pt = p >> 4, fr = p & 15;
    #pragma unroll
    for (int e = 0; e < 4; ++e) {
        int kk = t + e * 256;
        int kc = kk >> 5, qd = (kk >> 3) & 3, j = kk & 7;
        YbF[((size_t)pt * 32 + kc) * 512 + (qd * 16 + fr) * 8 + j] = f2bf(vals[e] * rinv);
    }
}

// ---------------------------------------------------------------------------
// K5: deconv weights in MFMA B-fragment order:
// RWtF[mt=c][kc][lane=qd*16+uv][j] = RWt[c*16+uv][kc*32+qd*8+j],
// RWt[m][k] = b~[c, 2*(k&31)-1+u, 2*(k>>5)-1+v].
__global__ void k5_rwt(const float* __restrict__ b, float* __restrict__ ws) {
    int n = blockIdx.x, c = blockIdx.y;
    int t = threadIdx.x;
    __shared__ float pl[64][65];
    const float* bp = b + ((size_t)n * NC + c) * (HF * HF);
    for (int e = 0; e < 16; ++e) {
        int idx = t + e * 256;
        pl[idx >> 6][idx & 63] = bp[idx];
    }
    __syncthreads();
    unsigned short* RWtF = (unsigned short*)((char*)ws + RWT_B) + (size_t)n * MN * L
                           + (size_t)c * 32 * 512;
    #pragma unroll
    for (int uv = 0; uv < 16; ++uv) {
        int u = uv >> 2, v = uv & 3;
        for (int e = 0; e < 4; ++e) {
            int k = t + e * 256;
            int ly = k & 31, lx = k >> 5;
            int r = 2 * ly - 1 + u, s = 2 * lx - 1 + v;
            float val = (r >= 0 && r < HF && s >= 0 && s < HF) ? pl[r][s] : 0.f;
            int kc = k >> 5, qd = (k >> 3) & 3, j = k & 7;
            RWtF[(size_t)kc * 512 + (qd * 16 + uv) * 8 + j] = f2bf(val);
        }
    }
}

// ---------------------------------------------------------------------------
// K6: Z[p][m] = sum_k Yb[p][k] * RWt[m][k] via bf16 MFMA 16x16x32.
// LDS-free, barrier-free: operands are pre-laid-out in fragment order, each
// fragment is ONE fully-coalesced 1 KB global load (lane l reads [l*16B]).
// Register double-buffer over kc.  Grid (8,12,8): x = n (XCD pin).
__global__ __launch_bounds__(256) void k6_mfma_z(float* __restrict__ ws) {
    int n = blockIdx.x;
    int wv = threadIdx.x >> 6, lane = threadIdx.x & 63;
    int pt0 = blockIdx.z * 8 + (wv >> 1) * 4;
    int mt0 = blockIdx.y * 8 + (wv & 1) * 4;

    const unsigned short* YbF = (const unsigned short*)((const char*)ws + YB_B)
                                + (size_t)n * L * L + lane * 8;
    const unsigned short* RWtF = (const unsigned short*)((const char*)ws + RWT_B)
                                 + (size_t)n * MN * L + lane * 8;

    float4v acc[4][4] = {};
    short8 af[2][4], bf[2][4];
    #pragma unroll
    for (int a = 0; a < 4; ++a) {
        af[0][a] = *(const short8*)(YbF + ((size_t)(pt0 + a) * 32) * 512);
        bf[0][a] = *(const short8*)(RWtF + ((size_t)(mt0 + a) * 32) * 512);
    }
    for (int kc = 0; kc < 32; ++kc) {
        int cur = kc & 1, nxt = cur ^ 1;
        if (kc < 31) {
            #pragma unroll
            for (int a = 0; a < 4; ++a) {
                af[nxt][a] = *(const short8*)(YbF + ((size_t)(pt0 + a) * 32 + kc + 1) * 512);
                bf[nxt][a] = *(const short8*)(RWtF + ((size_t)(mt0 + a) * 32 + kc + 1) * 512);
            }
        }
        #pragma unroll
        for (int a = 0; a < 4; ++a)
            #pragma unroll
            for (int bq = 0; bq < 4; ++bq)
                acc[a][bq] = __builtin_amdgcn_mfma_f32_16x16x32_bf16(
                    af[cur][a], bf[cur][bq], acc[a][bq], 0, 0, 0);
    }

    int fr = lane & 15, qd = lane >> 4;
    float* Zp = ws + Z_OFF + (size_t)n * L * MN;
    #pragma unroll
    for (int a = 0; a < 4; ++a) {
        #pragma unroll
        for (int r = 0; r < 4; ++r) {
            int p = (pt0 + a) * 16 + qd * 4 + r;
            #pragma unroll
            for (int bq = 0; bq < 4; ++bq) {
                int m = (mt0 + bq) * 16 + fr;
                Zp[(size_t)p * MN + m] = acc[a][bq][r];
            }
        }
    }
}

// ---------------------------------------------------------------------------
// K7: gather epilogue.  Grid (8,16,96): x = n (XCD pin — Z(n) from k6's L2).
__global__ __launch_bounds__(256) void k7_gather(const float* __restrict__ ws,
                                                 float* __restrict__ out) {
    int n = blockIdx.x, yq = blockIdx.y, c = blockIdx.z;
    int t = threadIdx.x;
    int y0 = yq * 4;
    int ibase = (y0 >> 1) - 1;
    __shared__ float zs[128][17];
    const float* Zp = ws + Z_OFF + (size_t)n * L * MN;
    #pragma unroll
    for (int e = 0; e < 2; ++e) {
        int idx = t + e * 256;
        int pl = idx >> 2, q = idx & 3;
        int il = pl >> 5, j = pl & 31;
        int i = ibase + il;
        float4 v = make_float4(0.f, 0.f, 0.f, 0.f);
        if (i >= 0 && i < HS)
            v = *(const float4*)&Zp[(size_t)(i * HS + j) * MN + c * 16 + q * 4];
        zs[pl][q * 4 + 0] = v.x;
        zs[pl][q * 4 + 1] = v.y;
        zs[pl][q * 4 + 2] = v.z;
        zs[pl][q * 4 + 3] = v.w;
    }
    __syncthreads();
    int y = y0 + (t >> 6), x = t & 63;
    int ih = (y + 1) >> 1, jh = (x + 1) >> 1;
    float s = 0.f;
    #pragma unroll
    for (int di = 0; di < 2; ++di) {
        int i = ih - di;
        if (i < 0 || i >= HS) continue;
        int u = y + 1 - 2 * i;
        int il = i - ibase;
        #pragma unroll
        for (int dj = 0; dj < 2; ++dj) {
            int j = jh - dj;
            if (j < 0 || j >= HS) continue;
            int v = x + 1 - 2 * j;
            s += zs[il * 32 + j][u * 4 + v];
        }
    }
    out[(((size_t)n * NC + c) * HF + y) * HF + x] = 0.25f * s;
}

// ---------------------------------------------------------------------------
extern "C" void kernel_launch(void* const* d_in, const int* in_sizes, int n_in,
                              void* d_out, int out_size, void* d_ws, size_t ws_size,
                              hipStream_t stream) {
    const float* f = (const float*)d_in[0];
    const float* b = (const float*)d_in[1];
    float* out = (float*)d_out;
    float* ws = (float*)d_ws;

    kpre_pack<<<dim3(NB, NC, 2), 256, 0, stream>>>(f, b, ws);
    k0_norm<<<NB, 1024, 0, stream>>>(ws);
    k1_gram<<<dim3(NB, 8, 8), 256, 0, stream>>>(ws);
    k23_score_fuse1t<<<8192, 256, 0, stream>>>(ws);
    k4_fuse2_softmax<<<8192, 256, 0, stream>>>(ws);
    k5_rwt<<<dim3(NB, NC), 256, 0, stream>>>(b, ws);
    k6_mfma_z<<<dim3(NB, 12, 8), 256, 0, stream>>>(ws);
    k7_gather<<<dim3(NB, 16, NC), 256, 0, stream>>>(ws, out);
}